// Round 5
// baseline (1661.678 us; speedup 1.0000x reference)
//
#include <hip/hip_runtime.h>
#include <hip/hip_bf16.h>

// Problem: B=4, Tq=Tk=2048, E=1024, D=128, d=64.
// Round 5: RESOLVED dtype map — ALL inputs fp32, OUTPUT fp32 (the reference
// returns jnp.float32; the "(bf16" in the test label is a static string; the
// harness merely bf16-quantizes the np reference and uses a 2%*max|ref|
// threshold). Rounds 2-4 failed only because we wrote bf16 into a fp32
// buffer (pair-packing -> 0.455 signature). Pipeline math itself was
// brute-force-verified on-device by the round-3/4 checker (bits==0).
//   lam_kernel  : scalar lambda (fp32 in, fp32 out)
//   proj_kernel : Y = X @ W + b (fp32), DUAL computes K and V in one pass
//   attn_kernel : dual online-softmax flash attention, fp32 out
//   check_kernel: on-device brute-force tripwire (sentinel 1e6*(1+bits))

#define TQ 2048
#define TK 2048
#define EMB 1024
#define HD 128

// ---------------------------------------------------------------- lambda ----
__global__ void lam_kernel(const float* __restrict__ lq1, const float* __restrict__ lk1,
                           const float* __restrict__ lq2, const float* __restrict__ lk2,
                           const float* __restrict__ linit, float* __restrict__ lam_out) {
  int j = threadIdx.x;  // 64 threads
  float s1 = lq1[j] * lk1[j] + lq1[j + 64] * lk1[j + 64];
  float s2 = lq2[j] * lk2[j] + lq2[j + 64] * lk2[j + 64];
  for (int off = 1; off < 64; off <<= 1) {
    s1 += __shfl_xor(s1, off);
    s2 += __shfl_xor(s2, off);
  }
  if (j == 0) lam_out[0] = __expf(s1) - __expf(s2) + linit[0];
}

// ------------------------------------------------------------ projection ----
// Block: 256 threads, 16 rows x 128 cols. Wave w -> rows {w, w+4, w+8, w+12};
// lane j -> cols {2j, 2j+1}. X staged in LDS (wave-uniform broadcast reads);
// W loads coalesced (64 lanes x 8B contiguous).
template <bool DUAL>
__global__ __launch_bounds__(256) void proj_kernel(
    const float* __restrict__ X,
    const float* __restrict__ W1, const float* __restrict__ B1, float* __restrict__ Y1,
    const float* __restrict__ W2, const float* __restrict__ B2, float* __restrict__ Y2) {
  __shared__ __align__(16) float xs[16][EMB];  // 64 KB
  const int t = threadIdx.x;
  const size_t m0 = (size_t)blockIdx.x * 16;

#pragma unroll
  for (int i = 0; i < 16; ++i) {
    int c = t + 256 * i;  // 4096 float4 chunks
    int row = c >> 8;
    int off = (c & 255) * 4;
    *(float4*)&xs[row][off] = *(const float4*)&X[(m0 + row) * EMB + off];
  }
  __syncthreads();

  const int n0 = (t & 63) * 2;
  const int h = t >> 6;
  float a1[4][2] = {{0.f, 0.f}, {0.f, 0.f}, {0.f, 0.f}, {0.f, 0.f}};
  float a2[4][2] = {{0.f, 0.f}, {0.f, 0.f}, {0.f, 0.f}, {0.f, 0.f}};

  for (int k = 0; k < EMB; k += 2) {
    float2 w1a = *(const float2*)&W1[(size_t)k * HD + n0];
    float2 w1b = *(const float2*)&W1[(size_t)(k + 1) * HD + n0];
    float2 w2a, w2b;
    if (DUAL) {
      w2a = *(const float2*)&W2[(size_t)k * HD + n0];
      w2b = *(const float2*)&W2[(size_t)(k + 1) * HD + n0];
    }
#pragma unroll
    for (int ri = 0; ri < 4; ++ri) {
      float2 xv = *(const float2*)&xs[h + 4 * ri][k];
      a1[ri][0] += xv.x * w1a.x + xv.y * w1b.x;
      a1[ri][1] += xv.x * w1a.y + xv.y * w1b.y;
      if (DUAL) {
        a2[ri][0] += xv.x * w2a.x + xv.y * w2b.x;
        a2[ri][1] += xv.x * w2a.y + xv.y * w2b.y;
      }
    }
  }

  float2 bb1 = *(const float2*)&B1[n0];
  float2 bb2;
  if (DUAL) bb2 = *(const float2*)&B2[n0];
#pragma unroll
  for (int ri = 0; ri < 4; ++ri) {
    size_t row = m0 + h + 4 * ri;
    *(float2*)&Y1[row * HD + n0] = make_float2(a1[ri][0] + bb1.x, a1[ri][1] + bb1.y);
    if (DUAL)
      *(float2*)&Y2[row * HD + n0] = make_float2(a2[ri][0] + bb2.x, a2[ri][1] + bb2.y);
  }
}

// ------------------------------------------------------------- attention ----
// grid (TQ/16, B), block 256 (4 waves). Wave w -> q-rows {4w..4w+3}. Per
// 32-key tile: lane j = (h=j>>5, tk=j&31) computes the full score
// s_{h+1}[tk]; 5-step shuffle reductions per 32-group; P via LDS so all 64
// lanes accumulate o[j], o[j+64] for both softmaxes. Brute-force verified
// on-device (rounds 3/4, bits==0).
__global__ __launch_bounds__(256) void attn_kernel(
    const float* __restrict__ qf, const float* __restrict__ kf,
    const float* __restrict__ vf, const float* __restrict__ lam_ptr,
    float* __restrict__ out) {
  __shared__ __align__(16) float qs[16][HD];   // 8 KB
  __shared__ __align__(16) float KT[HD][33];   // 16.9 KB (transposed, +1 pad)
  __shared__ __align__(16) float Vs[32][HD];   // 16 KB
  __shared__ float pbuf[4][4][2][32];          // 4 KB
  __shared__ float abuf[4][4][2];

  const int t = threadIdx.x;
  const int b = blockIdx.y;
  const int q0 = blockIdx.x * 16;
  const int w = t >> 6;
  const int j = t & 63;
  const int h = j >> 5;
  const int tk = j & 31;
  const float lam = lam_ptr[0];

#pragma unroll
  for (int i = 0; i < 2; ++i) {
    int c = t + 256 * i;
    int row = c >> 5;
    int off = (c & 31) * 4;
    *(float4*)&qs[row][off] =
        *(const float4*)&qf[((size_t)(b * TQ + q0 + row)) * HD + off];
  }

  float m[4], l[4];
  float o1lo[4], o1hi[4], o2lo[4], o2hi[4];
#pragma unroll
  for (int r = 0; r < 4; ++r) {
    m[r] = -1e30f; l[r] = 0.f;
    o1lo[r] = o1hi[r] = o2lo[r] = o2hi[r] = 0.f;
  }
  __syncthreads();

  for (int kt = 0; kt < TK; kt += 32) {
#pragma unroll
    for (int i = 0; i < 4; ++i) {
      int c = t + 256 * i;
      int key = c >> 5;
      int off = (c & 31) * 4;
      size_t g = ((size_t)(b * TK + kt + key)) * HD + off;
      float4 kv = *(const float4*)&kf[g];
      KT[off + 0][key] = kv.x;
      KT[off + 1][key] = kv.y;
      KT[off + 2][key] = kv.z;
      KT[off + 3][key] = kv.w;
      *(float4*)&Vs[key][off] = *(const float4*)&vf[g];
    }
    __syncthreads();

#pragma unroll
    for (int r = 0; r < 4; ++r) {
      const int row = w * 4 + r;
      const float* qrow = &qs[row][h * 64];
      float s = 0.f;
#pragma unroll 8
      for (int d = 0; d < 64; ++d) s += qrow[d] * KT[h * 64 + d][tk];
      s *= 0.125f;  // 1/sqrt(64)
      float mt = s;
      for (int off = 1; off < 32; off <<= 1) mt = fmaxf(mt, __shfl_xor(mt, off));
      float mnew = fmaxf(m[r], mt);
      float p = __expf(s - mnew);
      float alpha = __expf(m[r] - mnew);
      float lt = p;
      for (int off = 1; off < 32; off <<= 1) lt += __shfl_xor(lt, off);
      l[r] = l[r] * alpha + lt;
      m[r] = mnew;
      pbuf[w][r][h][tk] = p;
      if (tk == 0) abuf[w][r][h] = alpha;
    }
    __syncthreads();

#pragma unroll
    for (int r = 0; r < 4; ++r) {
      float al1 = abuf[w][r][0];
      float al2 = abuf[w][r][1];
      o1lo[r] *= al1; o1hi[r] *= al1;
      o2lo[r] *= al2; o2hi[r] *= al2;
#pragma unroll 4
      for (int tt = 0; tt < 32; ++tt) {
        float p1 = pbuf[w][r][0][tt];
        float p2 = pbuf[w][r][1][tt];
        float vlo = Vs[tt][j];
        float vhi = Vs[tt][64 + j];
        o1lo[r] += p1 * vlo; o1hi[r] += p1 * vhi;
        o2lo[r] += p2 * vlo; o2hi[r] += p2 * vhi;
      }
    }
    __syncthreads();
  }

#pragma unroll
  for (int r = 0; r < 4; ++r) {
    float lv = l[r];  // lanes 0..31 hold l1, lanes 32..63 hold l2
    float l1 = __shfl(lv, 0);
    float l2 = __shfl(lv, 32);
    float rlo = o1lo[r] / l1 - lam * (o2lo[r] / l2);
    float rhi = o1hi[r] / l1 - lam * (o2hi[r] / l2);
    size_t base = ((size_t)(b * TQ + q0 + w * 4 + r)) * HD;
    out[base + j] = rlo;
    out[base + 64 + j] = rhi;
  }
}

// --------------------------------------------------------------- checker ----
// 1 wave tripwire. On ANY failed check writes sentinel 1e6*(1+bits) to out[0]
// (dominates legit values ~0.3): bit0=lambda bit1=proj bit2=NaN bit3=attn.
__device__ __forceinline__ float wsumf(float v) {
  for (int o = 1; o < 64; o <<= 1) v += __shfl_xor(v, o);
  return v;
}
__device__ __forceinline__ float wmaxf(float v) {
  for (int o = 1; o < 64; o <<= 1) v = fmaxf(v, __shfl_xor(v, o));
  return v;
}

__global__ void check_kernel(
    const float* x, const float* enc, const float* Wq, const float* bq,
    const float* Wk, const float* bk, const float* Wv, const float* bv,
    const float* lq1, const float* lk1, const float* lq2, const float* lk2,
    const float* linit, const float* lamp,
    const float* qf, const float* kf, const float* vf, float* out) {
  const int j = threadIdx.x;  // 64
  int bits = 0;

  float s1 = lq1[j] * lk1[j] + lq1[j + 64] * lk1[j + 64];
  float s2 = lq2[j] * lk2[j] + lq2[j + 64] * lk2[j + 64];
  s1 = wsumf(s1); s2 = wsumf(s2);
  float lam_b = __expf(s1) - __expf(s2) + linit[0];
  float lamv = lamp[0];
  if (!(fabsf(lam_b - lamv) <= 0.01f)) bits |= 1;

  {
    const int which[7] = {0, 0, 0, 1, 1, 2, 2};
    const int prow[7] = {0, 8191, 4000, 0, 5000, 3000, 1};
    const int pcol[7] = {0, 127, 64, 0, 77, 127, 1};
    for (int pi = 0; pi < 7; ++pi) {
      const float* X = (which[pi] == 0) ? x : enc;
      const float* W = (which[pi] == 0) ? Wq : (which[pi] == 1) ? Wk : Wv;
      const float* Bb = (which[pi] == 0) ? bq : (which[pi] == 1) ? bk : bv;
      const float* Y = (which[pi] == 0) ? qf : (which[pi] == 1) ? kf : vf;
      float acc = 0.f;
      for (int kk = j; kk < EMB; kk += 64)
        acc += X[(size_t)prow[pi] * EMB + kk] * W[(size_t)kk * HD + pcol[pi]];
      acc = wsumf(acc);
      acc += Bb[pcol[pi]];
      float got = Y[(size_t)prow[pi] * HD + pcol[pi]];
      if (!(fabsf(acc - got) <= 0.02f * fmaxf(1.f, fabsf(acc)))) bits |= 2;
    }
  }

  {
    const int pb[4] = {0, 1, 3, 2};
    const int pq[4] = {0, 17, 2047, 1023};
    const int pd[4] = {0, 5, 127, 64};
    for (int pi = 0; pi < 4; ++pi) {
      const size_t row = (size_t)pb[pi] * TQ + pq[pi];
      const float* qr = &qf[row * HD];
      float m1 = -1e30f, m2 = -1e30f;
      for (int t0 = 0; t0 < TK / 64; ++t0) {
        int key = j + 64 * t0;
        const float* kr = &kf[((size_t)pb[pi] * TK + key) * HD];
        float a = 0.f, c = 0.f;
        for (int d = 0; d < 64; ++d) { a += qr[d] * kr[d]; c += qr[d + 64] * kr[d + 64]; }
        m1 = fmaxf(m1, a * 0.125f);
        m2 = fmaxf(m2, c * 0.125f);
      }
      m1 = wmaxf(m1); m2 = wmaxf(m2);
      float l1 = 0.f, l2 = 0.f, o1 = 0.f, o2 = 0.f;
      for (int t0 = 0; t0 < TK / 64; ++t0) {
        int key = j + 64 * t0;
        const float* kr = &kf[((size_t)pb[pi] * TK + key) * HD];
        float a = 0.f, c = 0.f;
        for (int d = 0; d < 64; ++d) { a += qr[d] * kr[d]; c += qr[d + 64] * kr[d + 64]; }
        float p1 = __expf(a * 0.125f - m1);
        float p2 = __expf(c * 0.125f - m2);
        l1 += p1; l2 += p2;
        float vv = vf[((size_t)pb[pi] * TK + key) * HD + pd[pi]];
        o1 += p1 * vv; o2 += p2 * vv;
      }
      l1 = wsumf(l1); l2 = wsumf(l2); o1 = wsumf(o1); o2 = wsumf(o2);
      float res = o1 / l1 - lamv * (o2 / l2);
      float outv = out[row * HD + pd[pi]];
      if (!(fabsf(outv) <= 1e6f)) bits |= 4;
      if (!(fabsf(res - outv) <= 0.02f)) bits |= 8;
    }
  }

  if (j == 0 && bits) out[0] = 1.0e6f * (float)(1 + bits);
}

extern "C" void kernel_launch(void* const* d_in, const int* in_sizes, int n_in,
                              void* d_out, int out_size, void* d_ws, size_t ws_size,
                              hipStream_t stream) {
  const float* x    = (const float*)d_in[0];
  const float* enc  = (const float*)d_in[1];
  const float* Wq   = (const float*)d_in[2];
  const float* bq   = (const float*)d_in[3];
  const float* Wk   = (const float*)d_in[4];
  const float* bk   = (const float*)d_in[5];
  const float* Wv   = (const float*)d_in[6];
  const float* bv   = (const float*)d_in[7];
  const float* lq1  = (const float*)d_in[8];
  const float* lk1  = (const float*)d_in[9];
  const float* lq2  = (const float*)d_in[10];
  const float* lk2  = (const float*)d_in[11];
  const float* lini = (const float*)d_in[12];
  float* out = (float*)d_out;

  const int Mq = 4 * TQ;  // 8192
  float* lam = (float*)d_ws;
  float* qf = (float*)((char*)d_ws + 256);
  float* kf = qf + (size_t)Mq * HD;
  float* vf = kf + (size_t)Mq * HD;

  hipLaunchKernelGGL(lam_kernel, dim3(1), dim3(64), 0, stream,
                     lq1, lk1, lq2, lk2, lini, lam);
  hipLaunchKernelGGL((proj_kernel<false>), dim3(Mq / 16), dim3(256), 0, stream,
                     x, Wq, bq, qf, (const float*)nullptr, (const float*)nullptr,
                     (float*)nullptr);
  hipLaunchKernelGGL((proj_kernel<true>), dim3(Mq / 16), dim3(256), 0, stream,
                     enc, Wk, bk, kf, Wv, bv, vf);
  hipLaunchKernelGGL(attn_kernel, dim3(TQ / 16, 4), dim3(256), 0, stream,
                     qf, kf, vf, lam, out);
  hipLaunchKernelGGL(check_kernel, dim3(1), dim3(64), 0, stream,
                     x, enc, Wq, bq, Wk, bk, Wv, bv, lq1, lk1, lq2, lk2, lini,
                     lam, qf, kf, vf, out);
}

// Round 6
// 431.679 us; speedup vs baseline: 3.8493x; 3.8493x over previous
//
#include <hip/hip_runtime.h>
#include <hip/hip_bf16.h>

// Problem: B=4, Tq=Tk=2048, E=1024, D=128, d=64. All inputs fp32, output fp32.
// Round 6: MFMA attention. Proj stays VALU (verified) but now emits bf16:
//   qb  [8192][128] bf16, pre-scaled by 0.125 (exact in bf16)
//   kb  [8192][128] bf16
//   vbT [128][8192] bf16 (transposed at epilogue -> attn stages V with no
//                         in-LDS transpose)
// attn: per block 64 q-rows, 4 waves x 16 rows; per 64-key tile:
//   QK^T (16 MFMA) -> dual online softmax in C/D layout (quad-group shuffle
//   reductions) -> P to LDS (bf16, A-layout round trip, m120 pattern) ->
//   PV (32 MFMA) -> fp32 epilogue O1/l1 - lam*O2/l2.
// attn_check_kernel: 128-block parallel brute-force tripwire; sentinel 1e7
// in out[0] ONLY on mismatch (>0.02) -> failing absmax decodes the stage.

#define TQ 2048
#define TK 2048
#define EMB 1024
#define HD 128
#define MQ 8192  // B*Tq rows

typedef __attribute__((ext_vector_type(8))) short short8;   // 8 bf16 = 4 VGPR
typedef __attribute__((ext_vector_type(4))) float floatx4;  // MFMA acc

__device__ __forceinline__ unsigned short f2bf(float f) {  // RNE fp32->bf16
  union { float f; unsigned u; } v; v.f = f;
  unsigned r = v.u + 0x7fffu + ((v.u >> 16) & 1u);
  return (unsigned short)(r >> 16);
}
__device__ __forceinline__ float bf2f(unsigned short s) {
  union { unsigned u; float f; } v; v.u = ((unsigned)s) << 16;
  return v.f;
}

// ---------------------------------------------------------------- lambda ----
__global__ void lam_kernel(const float* __restrict__ lq1, const float* __restrict__ lk1,
                           const float* __restrict__ lq2, const float* __restrict__ lk2,
                           const float* __restrict__ linit, float* __restrict__ lam_out) {
  int j = threadIdx.x;  // 64 threads
  float s1 = lq1[j] * lk1[j] + lq1[j + 64] * lk1[j + 64];
  float s2 = lq2[j] * lk2[j] + lq2[j + 64] * lk2[j + 64];
  for (int off = 1; off < 64; off <<= 1) {
    s1 += __shfl_xor(s1, off);
    s2 += __shfl_xor(s2, off);
  }
  if (j == 0) lam_out[0] = __expf(s1) - __expf(s2) + linit[0];
}

// ------------------------------------------------------------ projection ----
// Verified round-5 core; epilogue now emits bf16. non-DUAL: Y1=qb (scale
// 0.125). DUAL: Y1=kb (row-major), Y2t=vbT (transposed [feat][row]).
template <bool DUAL>
__global__ __launch_bounds__(256) void proj_kernel(
    const float* __restrict__ X,
    const float* __restrict__ W1, const float* __restrict__ B1,
    unsigned short* __restrict__ Y1, float scale1,
    const float* __restrict__ W2, const float* __restrict__ B2,
    unsigned short* __restrict__ Y2t) {
  __shared__ __align__(16) float xs[16][EMB];  // 64 KB
  const int t = threadIdx.x;
  const size_t m0 = (size_t)blockIdx.x * 16;

#pragma unroll
  for (int i = 0; i < 16; ++i) {
    int c = t + 256 * i;  // 4096 float4 chunks
    int row = c >> 8;
    int off = (c & 255) * 4;
    *(float4*)&xs[row][off] = *(const float4*)&X[(m0 + row) * EMB + off];
  }
  __syncthreads();

  const int n0 = (t & 63) * 2;
  const int h = t >> 6;
  float a1[4][2] = {{0.f, 0.f}, {0.f, 0.f}, {0.f, 0.f}, {0.f, 0.f}};
  float a2[4][2] = {{0.f, 0.f}, {0.f, 0.f}, {0.f, 0.f}, {0.f, 0.f}};

  for (int k = 0; k < EMB; k += 2) {
    float2 w1a = *(const float2*)&W1[(size_t)k * HD + n0];
    float2 w1b = *(const float2*)&W1[(size_t)(k + 1) * HD + n0];
    float2 w2a, w2b;
    if (DUAL) {
      w2a = *(const float2*)&W2[(size_t)k * HD + n0];
      w2b = *(const float2*)&W2[(size_t)(k + 1) * HD + n0];
    }
#pragma unroll
    for (int ri = 0; ri < 4; ++ri) {
      float2 xv = *(const float2*)&xs[h + 4 * ri][k];
      a1[ri][0] += xv.x * w1a.x + xv.y * w1b.x;
      a1[ri][1] += xv.x * w1a.y + xv.y * w1b.y;
      if (DUAL) {
        a2[ri][0] += xv.x * w2a.x + xv.y * w2b.x;
        a2[ri][1] += xv.x * w2a.y + xv.y * w2b.y;
      }
    }
  }

  float2 bb1 = *(const float2*)&B1[n0];
  float2 bb2;
  if (DUAL) bb2 = *(const float2*)&B2[n0];
#pragma unroll
  for (int ri = 0; ri < 4; ++ri) {
    size_t row = m0 + h + 4 * ri;
    float y0 = (a1[ri][0] + bb1.x) * scale1;
    float y1 = (a1[ri][1] + bb1.y) * scale1;
    unsigned pack = (unsigned)f2bf(y0) | ((unsigned)f2bf(y1) << 16);
    *(unsigned*)&Y1[row * HD + n0] = pack;
    if (DUAL) {
      float v0 = a2[ri][0] + bb2.x;
      float v1 = a2[ri][1] + bb2.y;
      Y2t[(size_t)n0 * MQ + row] = f2bf(v0);
      Y2t[(size_t)(n0 + 1) * MQ + row] = f2bf(v1);
    }
  }
}

// ------------------------------------------------------------- attention ----
// grid (TQ/64, B), block 256 (4 waves, wave w -> 16 q-rows).
// MFMA 16x16x32 bf16 layouts (m89/m91/m120 verified):
//   A-frag: lane holds A[m=lane&15][k=quad*8+j], j=0..7 (short8)
//   B-frag: lane holds B[k=quad*8+j][n=lane&15]
//   C/D   : lane holds D[row=quad*4+r][col=lane&15], r=0..3
__global__ __launch_bounds__(256) void attn_kernel(
    const unsigned short* __restrict__ qb, const unsigned short* __restrict__ kb,
    const unsigned short* __restrict__ vbT, const float* __restrict__ lam_ptr,
    float* __restrict__ out) {
  __shared__ __align__(16) unsigned short Kls[64][136];      // 17.4 KB, +8 pad
  __shared__ __align__(16) unsigned short Vt[128][72];       // 18.4 KB (V^T)
  __shared__ __align__(16) unsigned short Pls[4][2][16][72]; // 18.4 KB

  const int t = threadIdx.x;
  const int w = t >> 6;
  const int lane = t & 63;
  const int lo = lane & 15;
  const int quad = lane >> 4;
  const int q8 = quad * 8;
  const int b = blockIdx.y;
  const int q0 = blockIdx.x * 64;
  const float lam = lam_ptr[0];

  // Q A-frags (qb pre-scaled by 0.125): [half][kstep]
  const size_t qrow = (size_t)b * TQ + q0 + w * 16 + lo;
  short8 qf[2][2];
#pragma unroll
  for (int half = 0; half < 2; ++half)
#pragma unroll
    for (int ks = 0; ks < 2; ++ks)
      qf[half][ks] = *(const short8*)&qb[qrow * HD + half * 64 + ks * 32 + q8];

  floatx4 o1[8], o2[8];
  const floatx4 zz = {0.f, 0.f, 0.f, 0.f};
#pragma unroll
  for (int i = 0; i < 8; ++i) { o1[i] = zz; o2[i] = zz; }
  float m1[4], l1[4], m2[4], l2[4];
#pragma unroll
  for (int r = 0; r < 4; ++r) { m1[r] = m2[r] = -1e30f; l1[r] = l2[r] = 0.f; }

  for (int kt = 0; kt < TK; kt += 64) {
    // ---- stage K (row-major) + V^T (from pre-transposed vbT) ----
#pragma unroll
    for (int i = 0; i < 4; ++i) {
      int c = t + 256 * i;  // 1024 chunks of 8 bf16
      int key = c >> 4, f0 = (c & 15) * 8;
      *(int4*)&Kls[key][f0] =
          *(const int4*)&kb[((size_t)b * TK + kt + key) * HD + f0];
      int f = c >> 3, k0 = (c & 7) * 8;
      *(int4*)&Vt[f][k0] =
          *(const int4*)&vbT[(size_t)f * MQ + b * TK + kt + k0];
    }
    __syncthreads();

    // ---- QK^T: S1,S2 = 16x64 tiles ----
    floatx4 s1[4], s2[4];
#pragma unroll
    for (int i = 0; i < 4; ++i) { s1[i] = zz; s2[i] = zz; }
#pragma unroll
    for (int ks = 0; ks < 2; ++ks)
#pragma unroll
      for (int nt = 0; nt < 4; ++nt) {
        short8 kf1 = *(const short8*)&Kls[nt * 16 + lo][ks * 32 + q8];
        short8 kf2 = *(const short8*)&Kls[nt * 16 + lo][64 + ks * 32 + q8];
        s1[nt] = __builtin_amdgcn_mfma_f32_16x16x32_bf16(qf[0][ks], kf1, s1[nt], 0, 0, 0);
        s2[nt] = __builtin_amdgcn_mfma_f32_16x16x32_bf16(qf[1][ks], kf2, s2[nt], 0, 0, 0);
      }

    // ---- dual online softmax (rows owned by quad-group) ----
#pragma unroll
    for (int r = 0; r < 4; ++r) {
      float a = fmaxf(fmaxf(s1[0][r], s1[1][r]), fmaxf(s1[2][r], s1[3][r]));
      float c2 = fmaxf(fmaxf(s2[0][r], s2[1][r]), fmaxf(s2[2][r], s2[3][r]));
#pragma unroll
      for (int o = 1; o < 16; o <<= 1) {
        a = fmaxf(a, __shfl_xor(a, o));
        c2 = fmaxf(c2, __shfl_xor(c2, o));
      }
      float mn1 = fmaxf(m1[r], a), mn2 = fmaxf(m2[r], c2);
      float al1 = __expf(m1[r] - mn1), al2 = __expf(m2[r] - mn2);
      m1[r] = mn1; m2[r] = mn2;
      float ls1 = 0.f, ls2 = 0.f;
#pragma unroll
      for (int nt = 0; nt < 4; ++nt) {
        float p1 = __expf(s1[nt][r] - mn1);
        float p2 = __expf(s2[nt][r] - mn2);
        ls1 += p1; ls2 += p2;
        Pls[w][0][quad * 4 + r][nt * 16 + lo] = f2bf(p1);
        Pls[w][1][quad * 4 + r][nt * 16 + lo] = f2bf(p2);
      }
#pragma unroll
      for (int o = 1; o < 16; o <<= 1) {
        ls1 += __shfl_xor(ls1, o);
        ls2 += __shfl_xor(ls2, o);
      }
      l1[r] = l1[r] * al1 + ls1;
      l2[r] = l2[r] * al2 + ls2;
#pragma unroll
      for (int nt = 0; nt < 8; ++nt) { o1[nt][r] *= al1; o2[nt][r] *= al2; }
    }
    __syncthreads();  // P visible (cross-phase), staging still protected

    // ---- PV: O1 += P1*V, O2 += P2*V ----
#pragma unroll
    for (int ks = 0; ks < 2; ++ks) {
      short8 p1 = *(const short8*)&Pls[w][0][lo][ks * 32 + q8];
      short8 p2 = *(const short8*)&Pls[w][1][lo][ks * 32 + q8];
#pragma unroll
      for (int nt = 0; nt < 8; ++nt) {
        short8 vf = *(const short8*)&Vt[nt * 16 + lo][ks * 32 + q8];
        o1[nt] = __builtin_amdgcn_mfma_f32_16x16x32_bf16(p1, vf, o1[nt], 0, 0, 0);
        o2[nt] = __builtin_amdgcn_mfma_f32_16x16x32_bf16(p2, vf, o2[nt], 0, 0, 0);
      }
    }
    __syncthreads();  // before next K/Vt staging
  }

  // ---- epilogue ----
#pragma unroll
  for (int r = 0; r < 4; ++r) {
    float inv1 = 1.f / l1[r];
    float inv2 = lam / l2[r];
    size_t base = ((size_t)b * TQ + q0 + w * 16 + quad * 4 + r) * HD + lo;
#pragma unroll
    for (int nt = 0; nt < 8; ++nt)
      out[base + nt * 16] = o1[nt][r] * inv1 - o2[nt][r] * inv2;
  }
}

// --------------------------------------------------------------- tripwire ----
// 128 blocks x 256 threads; block verifies one (b,q,d) output point by brute
// force from qb/kb/vbT. Sentinel 1e7 -> out[0] ONLY on mismatch/NaN.
__global__ __launch_bounds__(256) void attn_check_kernel(
    const unsigned short* __restrict__ qb, const unsigned short* __restrict__ kb,
    const unsigned short* __restrict__ vbT, const float* __restrict__ lamp,
    float* __restrict__ out) {
  __shared__ float qsh[HD];
  __shared__ float sred[4][4];
  const int t = threadIdx.x;
  const int w = t >> 6, lane = t & 63;
  const int bb = blockIdx.x & 3;
  const int q = (int)((blockIdx.x * 997u + 13u) & 2047u);
  const int dc = (int)((blockIdx.x * 37u + 5u) & 127u);

  const unsigned short* qr = &qb[((size_t)bb * TQ + q) * HD];
  if (t < HD) qsh[t] = bf2f(qr[t]);
  __syncthreads();

  float mx1 = -1e30f, mx2 = -1e30f;
  for (int it = 0; it < 8; ++it) {
    int key = t + 256 * it;
    const unsigned* kr = (const unsigned*)&kb[((size_t)bb * TK + key) * HD];
    float s1 = 0.f, s2 = 0.f;
#pragma unroll 8
    for (int du = 0; du < 32; ++du) {
      unsigned u1 = kr[du], u2 = kr[32 + du];
      s1 += qsh[2 * du] * bf2f((unsigned short)u1) +
            qsh[2 * du + 1] * bf2f((unsigned short)(u1 >> 16));
      s2 += qsh[64 + 2 * du] * bf2f((unsigned short)u2) +
            qsh[64 + 2 * du + 1] * bf2f((unsigned short)(u2 >> 16));
    }
    mx1 = fmaxf(mx1, s1); mx2 = fmaxf(mx2, s2);
  }
  for (int o = 1; o < 64; o <<= 1) {
    mx1 = fmaxf(mx1, __shfl_xor(mx1, o));
    mx2 = fmaxf(mx2, __shfl_xor(mx2, o));
  }
  if (lane == 0) { sred[0][w] = mx1; sred[1][w] = mx2; }
  __syncthreads();
  mx1 = fmaxf(fmaxf(sred[0][0], sred[0][1]), fmaxf(sred[0][2], sred[0][3]));
  mx2 = fmaxf(fmaxf(sred[1][0], sred[1][1]), fmaxf(sred[1][2], sred[1][3]));
  __syncthreads();

  float l1 = 0.f, l2 = 0.f, o1 = 0.f, o2 = 0.f;
  for (int it = 0; it < 8; ++it) {
    int key = t + 256 * it;
    const unsigned* kr = (const unsigned*)&kb[((size_t)bb * TK + key) * HD];
    float s1 = 0.f, s2 = 0.f;
#pragma unroll 8
    for (int du = 0; du < 32; ++du) {
      unsigned u1 = kr[du], u2 = kr[32 + du];
      s1 += qsh[2 * du] * bf2f((unsigned short)u1) +
            qsh[2 * du + 1] * bf2f((unsigned short)(u1 >> 16));
      s2 += qsh[64 + 2 * du] * bf2f((unsigned short)u2) +
            qsh[64 + 2 * du + 1] * bf2f((unsigned short)(u2 >> 16));
    }
    float p1 = __expf(s1 - mx1), p2 = __expf(s2 - mx2);
    float v = bf2f(vbT[(size_t)dc * MQ + bb * TK + key]);
    l1 += p1; l2 += p2; o1 += p1 * v; o2 += p2 * v;
  }
  for (int o = 1; o < 64; o <<= 1) {
    l1 += __shfl_xor(l1, o); l2 += __shfl_xor(l2, o);
    o1 += __shfl_xor(o1, o); o2 += __shfl_xor(o2, o);
  }
  if (lane == 0) { sred[0][w] = l1; sred[1][w] = l2; sred[2][w] = o1; sred[3][w] = o2; }
  __syncthreads();
  if (t == 0) {
    l1 = sred[0][0] + sred[0][1] + sred[0][2] + sred[0][3];
    l2 = sred[1][0] + sred[1][1] + sred[1][2] + sred[1][3];
    o1 = sred[2][0] + sred[2][1] + sred[2][2] + sred[2][3];
    o2 = sred[3][0] + sred[3][1] + sred[3][2] + sred[3][3];
    float res = o1 / l1 - lamp[0] * (o2 / l2);
    float got = out[((size_t)bb * TQ + q) * HD + dc];
    if (!(fabsf(res - got) <= 0.02f)) out[0] = 1.0e7f;  // NaN fires too
  }
}

extern "C" void kernel_launch(void* const* d_in, const int* in_sizes, int n_in,
                              void* d_out, int out_size, void* d_ws, size_t ws_size,
                              hipStream_t stream) {
  const float* x    = (const float*)d_in[0];
  const float* enc  = (const float*)d_in[1];
  const float* Wq   = (const float*)d_in[2];
  const float* bq   = (const float*)d_in[3];
  const float* Wk   = (const float*)d_in[4];
  const float* bk   = (const float*)d_in[5];
  const float* Wv   = (const float*)d_in[6];
  const float* bv   = (const float*)d_in[7];
  const float* lq1  = (const float*)d_in[8];
  const float* lk1  = (const float*)d_in[9];
  const float* lq2  = (const float*)d_in[10];
  const float* lk2  = (const float*)d_in[11];
  const float* lini = (const float*)d_in[12];
  float* out = (float*)d_out;

  float* lam = (float*)d_ws;
  unsigned short* qb  = (unsigned short*)((char*)d_ws + 256);
  unsigned short* kb  = qb + (size_t)MQ * HD;
  unsigned short* vbT = kb + (size_t)MQ * HD;  // [128][8192]

  hipLaunchKernelGGL(lam_kernel, dim3(1), dim3(64), 0, stream,
                     lq1, lk1, lq2, lk2, lini, lam);
  hipLaunchKernelGGL((proj_kernel<false>), dim3(MQ / 16), dim3(256), 0, stream,
                     x, Wq, bq, qb, 0.125f,
                     (const float*)nullptr, (const float*)nullptr,
                     (unsigned short*)nullptr);
  hipLaunchKernelGGL((proj_kernel<true>), dim3(MQ / 16), dim3(256), 0, stream,
                     enc, Wk, bk, kb, 1.0f, Wv, bv, vbT);
  hipLaunchKernelGGL(attn_kernel, dim3(TQ / 64, 4), dim3(256), 0, stream,
                     qb, kb, vbT, lam, out);
  hipLaunchKernelGGL(attn_check_kernel, dim3(128), dim3(256), 0, stream,
                     qb, kb, vbT, lam, out);
}

// Round 7
// 305.300 us; speedup vs baseline: 5.4428x; 1.4140x over previous
//
#include <hip/hip_runtime.h>
#include <hip/hip_bf16.h>

// Problem: B=4, Tq=Tk=2048, E=1024, D=128, d=64. All inputs fp32, output fp32.
// Round 7: MFMA projections (round 6's 330us VALU proj was 77% of runtime).
//   cvtWT_kernel    : W[1024][128] fp32 -> WT[128][1024] bf16 (B^T operand)
//   gemm_proj_kernel: grid(128,3) -> {q,k,v}. Per block 64x128 out, BK=64,
//                     2-barrier K-loop; A staged fp32 in LDS, converted to
//                     bf16 at frag build; fp32 accum; bias + 0.125 q-scale in
//                     epilogue; v stored transposed (packed 8B stores).
//   attn_kernel     : unchanged round-6 MFMA flash attention (verified).
//   attn_check_kernel: unchanged tripwire (sentinel 1e7 on mismatch).

#define TQ 2048
#define TK 2048
#define EMB 1024
#define HD 128
#define MQ 8192  // B*Tq rows

typedef __attribute__((ext_vector_type(8))) short short8;   // 8 bf16 = 4 VGPR
typedef __attribute__((ext_vector_type(4))) float floatx4;  // MFMA acc

__device__ __forceinline__ unsigned short f2bf(float f) {  // RNE fp32->bf16
  union { float f; unsigned u; } v; v.f = f;
  unsigned r = v.u + 0x7fffu + ((v.u >> 16) & 1u);
  return (unsigned short)(r >> 16);
}
__device__ __forceinline__ float bf2f(unsigned short s) {
  union { unsigned u; float f; } v; v.u = ((unsigned)s) << 16;
  return v.f;
}

// ---------------------------------------------------------------- lambda ----
__global__ void lam_kernel(const float* __restrict__ lq1, const float* __restrict__ lk1,
                           const float* __restrict__ lq2, const float* __restrict__ lk2,
                           const float* __restrict__ linit, float* __restrict__ lam_out) {
  int j = threadIdx.x;  // 64 threads
  float s1 = lq1[j] * lk1[j] + lq1[j + 64] * lk1[j + 64];
  float s2 = lq2[j] * lk2[j] + lq2[j + 64] * lk2[j + 64];
  for (int off = 1; off < 64; off <<= 1) {
    s1 += __shfl_xor(s1, off);
    s2 += __shfl_xor(s2, off);
  }
  if (j == 0) lam_out[0] = __expf(s1) - __expf(s2) + linit[0];
}

// -------------------------------------------------- weight convert+transpose
// WT[n][k] = bf16(W[k][n]); writes coalesced over k.
__global__ __launch_bounds__(256) void cvtWT_kernel(
    const float* __restrict__ Wq, const float* __restrict__ Wk,
    const float* __restrict__ Wv, unsigned short* __restrict__ WqT,
    unsigned short* __restrict__ WkT, unsigned short* __restrict__ WvT) {
  const int g = blockIdx.y;
  const float* W = (g == 0) ? Wq : (g == 1) ? Wk : Wv;
  unsigned short* WT = (g == 0) ? WqT : (g == 1) ? WkT : WvT;
  int idx = blockIdx.x * 256 + threadIdx.x;  // [0, 131072)
  int n = idx >> 10, k = idx & 1023;
  WT[idx] = f2bf(W[(size_t)k * HD + n]);
}

// -------------------------------------------------------- MFMA projections ----
// grid (MQ/64, 3). g=0: qb = (x@Wq+bq)*0.125 ; g=1: kb = enc@Wk+bk ;
// g=2: vbT[n][m] = enc@Wv+bv (transposed). 4 waves; wave w -> rows 16w..16w+15.
__global__ __launch_bounds__(256) void gemm_proj_kernel(
    const float* __restrict__ x, const float* __restrict__ enc,
    const unsigned short* __restrict__ WqT, const unsigned short* __restrict__ WkT,
    const unsigned short* __restrict__ WvT,
    const float* __restrict__ bq, const float* __restrict__ bk,
    const float* __restrict__ bv,
    unsigned short* __restrict__ qb, unsigned short* __restrict__ kb,
    unsigned short* __restrict__ vbT) {
  __shared__ __align__(16) float Alsf[64][68];           // 17.4 KB (+4 pad)
  __shared__ __align__(16) unsigned short Bls[128][72];  // 18.4 KB (+8 pad)
  const int t = threadIdx.x;
  const int w = t >> 6, lane = t & 63;
  const int lo = lane & 15, quad = lane >> 4, q8 = quad * 8;
  const int g = blockIdx.y;
  const size_t m0 = (size_t)blockIdx.x * 64;
  const float* A = (g == 0) ? x : enc;
  const unsigned short* BT = (g == 0) ? WqT : (g == 1) ? WkT : WvT;
  const float* bias = (g == 0) ? bq : (g == 1) ? bk : bv;

  floatx4 acc[8];
  const floatx4 zz = {0.f, 0.f, 0.f, 0.f};
#pragma unroll
  for (int i = 0; i < 8; ++i) acc[i] = zz;

  for (int kt = 0; kt < EMB; kt += 64) {
    // stage A (fp32 64x64) + B^T (bf16 128x64)
#pragma unroll
    for (int i = 0; i < 4; ++i) {
      int idx = t + 256 * i;
      int row = idx >> 4, c4 = (idx & 15) * 4;  // A: 1024 float4 chunks
      *(float4*)&Alsf[row][c4] = *(const float4*)&A[(m0 + row) * EMB + kt + c4];
      int n = idx >> 3, c8 = (idx & 7) * 8;     // B: 1024 int4 chunks
      *(int4*)&Bls[n][c8] = *(const int4*)&BT[(size_t)n * EMB + kt + c8];
    }
    __syncthreads();

#pragma unroll
    for (int ks = 0; ks < 2; ++ks) {
      float4 fa = *(const float4*)&Alsf[16 * w + lo][ks * 32 + q8];
      float4 fb = *(const float4*)&Alsf[16 * w + lo][ks * 32 + q8 + 4];
      short8 af;
      af[0] = (short)f2bf(fa.x); af[1] = (short)f2bf(fa.y);
      af[2] = (short)f2bf(fa.z); af[3] = (short)f2bf(fa.w);
      af[4] = (short)f2bf(fb.x); af[5] = (short)f2bf(fb.y);
      af[6] = (short)f2bf(fb.z); af[7] = (short)f2bf(fb.w);
#pragma unroll
      for (int nt = 0; nt < 8; ++nt) {
        short8 bfr = *(const short8*)&Bls[nt * 16 + lo][ks * 32 + q8];
        acc[nt] = __builtin_amdgcn_mfma_f32_16x16x32_bf16(af, bfr, acc[nt], 0, 0, 0);
      }
    }
    __syncthreads();
  }

  // epilogue: C/D layout row=quad*4+r, col=nt*16+lo
  const int mrow = 16 * w + quad * 4;
  if (g < 2) {
    unsigned short* Y = (g == 0) ? qb : kb;
    const float sc = (g == 0) ? 0.125f : 1.0f;
#pragma unroll
    for (int nt = 0; nt < 8; ++nt) {
      float bn = bias[nt * 16 + lo];
#pragma unroll
      for (int r = 0; r < 4; ++r)
        Y[(m0 + mrow + r) * HD + nt * 16 + lo] = f2bf((acc[nt][r] + bn) * sc);
    }
  } else {
#pragma unroll
    for (int nt = 0; nt < 8; ++nt) {
      float bn = bias[nt * 16 + lo];
      unsigned long long pk = 0;
#pragma unroll
      for (int r = 0; r < 4; ++r)
        pk |= (unsigned long long)f2bf(acc[nt][r] + bn) << (16 * r);
      *(unsigned long long*)&vbT[(size_t)(nt * 16 + lo) * MQ + m0 + mrow] = pk;
    }
  }
}

// ------------------------------------------------------------- attention ----
// Unchanged round-6 kernel (verified, absmax 1.95e-3).
__global__ __launch_bounds__(256) void attn_kernel(
    const unsigned short* __restrict__ qb, const unsigned short* __restrict__ kb,
    const unsigned short* __restrict__ vbT, const float* __restrict__ lam_ptr,
    float* __restrict__ out) {
  __shared__ __align__(16) unsigned short Kls[64][136];
  __shared__ __align__(16) unsigned short Vt[128][72];
  __shared__ __align__(16) unsigned short Pls[4][2][16][72];

  const int t = threadIdx.x;
  const int w = t >> 6;
  const int lane = t & 63;
  const int lo = lane & 15;
  const int quad = lane >> 4;
  const int q8 = quad * 8;
  const int b = blockIdx.y;
  const int q0 = blockIdx.x * 64;
  const float lam = lam_ptr[0];

  const size_t qrow = (size_t)b * TQ + q0 + w * 16 + lo;
  short8 qf[2][2];
#pragma unroll
  for (int half = 0; half < 2; ++half)
#pragma unroll
    for (int ks = 0; ks < 2; ++ks)
      qf[half][ks] = *(const short8*)&qb[qrow * HD + half * 64 + ks * 32 + q8];

  floatx4 o1[8], o2[8];
  const floatx4 zz = {0.f, 0.f, 0.f, 0.f};
#pragma unroll
  for (int i = 0; i < 8; ++i) { o1[i] = zz; o2[i] = zz; }
  float m1[4], l1[4], m2[4], l2[4];
#pragma unroll
  for (int r = 0; r < 4; ++r) { m1[r] = m2[r] = -1e30f; l1[r] = l2[r] = 0.f; }

  for (int kt = 0; kt < TK; kt += 64) {
#pragma unroll
    for (int i = 0; i < 4; ++i) {
      int c = t + 256 * i;
      int key = c >> 4, f0 = (c & 15) * 8;
      *(int4*)&Kls[key][f0] =
          *(const int4*)&kb[((size_t)b * TK + kt + key) * HD + f0];
      int f = c >> 3, k0 = (c & 7) * 8;
      *(int4*)&Vt[f][k0] =
          *(const int4*)&vbT[(size_t)f * MQ + b * TK + kt + k0];
    }
    __syncthreads();

    floatx4 s1[4], s2[4];
#pragma unroll
    for (int i = 0; i < 4; ++i) { s1[i] = zz; s2[i] = zz; }
#pragma unroll
    for (int ks = 0; ks < 2; ++ks)
#pragma unroll
      for (int nt = 0; nt < 4; ++nt) {
        short8 kf1 = *(const short8*)&Kls[nt * 16 + lo][ks * 32 + q8];
        short8 kf2 = *(const short8*)&Kls[nt * 16 + lo][64 + ks * 32 + q8];
        s1[nt] = __builtin_amdgcn_mfma_f32_16x16x32_bf16(qf[0][ks], kf1, s1[nt], 0, 0, 0);
        s2[nt] = __builtin_amdgcn_mfma_f32_16x16x32_bf16(qf[1][ks], kf2, s2[nt], 0, 0, 0);
      }

#pragma unroll
    for (int r = 0; r < 4; ++r) {
      float a = fmaxf(fmaxf(s1[0][r], s1[1][r]), fmaxf(s1[2][r], s1[3][r]));
      float c2 = fmaxf(fmaxf(s2[0][r], s2[1][r]), fmaxf(s2[2][r], s2[3][r]));
#pragma unroll
      for (int o = 1; o < 16; o <<= 1) {
        a = fmaxf(a, __shfl_xor(a, o));
        c2 = fmaxf(c2, __shfl_xor(c2, o));
      }
      float mn1 = fmaxf(m1[r], a), mn2 = fmaxf(m2[r], c2);
      float al1 = __expf(m1[r] - mn1), al2 = __expf(m2[r] - mn2);
      m1[r] = mn1; m2[r] = mn2;
      float ls1 = 0.f, ls2 = 0.f;
#pragma unroll
      for (int nt = 0; nt < 4; ++nt) {
        float p1 = __expf(s1[nt][r] - mn1);
        float p2 = __expf(s2[nt][r] - mn2);
        ls1 += p1; ls2 += p2;
        Pls[w][0][quad * 4 + r][nt * 16 + lo] = f2bf(p1);
        Pls[w][1][quad * 4 + r][nt * 16 + lo] = f2bf(p2);
      }
#pragma unroll
      for (int o = 1; o < 16; o <<= 1) {
        ls1 += __shfl_xor(ls1, o);
        ls2 += __shfl_xor(ls2, o);
      }
      l1[r] = l1[r] * al1 + ls1;
      l2[r] = l2[r] * al2 + ls2;
#pragma unroll
      for (int nt = 0; nt < 8; ++nt) { o1[nt][r] *= al1; o2[nt][r] *= al2; }
    }
    __syncthreads();

#pragma unroll
    for (int ks = 0; ks < 2; ++ks) {
      short8 p1 = *(const short8*)&Pls[w][0][lo][ks * 32 + q8];
      short8 p2 = *(const short8*)&Pls[w][1][lo][ks * 32 + q8];
#pragma unroll
      for (int nt = 0; nt < 8; ++nt) {
        short8 vf = *(const short8*)&Vt[nt * 16 + lo][ks * 32 + q8];
        o1[nt] = __builtin_amdgcn_mfma_f32_16x16x32_bf16(p1, vf, o1[nt], 0, 0, 0);
        o2[nt] = __builtin_amdgcn_mfma_f32_16x16x32_bf16(p2, vf, o2[nt], 0, 0, 0);
      }
    }
    __syncthreads();
  }

#pragma unroll
  for (int r = 0; r < 4; ++r) {
    float inv1 = 1.f / l1[r];
    float inv2 = lam / l2[r];
    size_t base = ((size_t)b * TQ + q0 + w * 16 + quad * 4 + r) * HD + lo;
#pragma unroll
    for (int nt = 0; nt < 8; ++nt)
      out[base + nt * 16] = o1[nt][r] * inv1 - o2[nt][r] * inv2;
  }
}

// --------------------------------------------------------------- tripwire ----
__global__ __launch_bounds__(256) void attn_check_kernel(
    const unsigned short* __restrict__ qb, const unsigned short* __restrict__ kb,
    const unsigned short* __restrict__ vbT, const float* __restrict__ lamp,
    float* __restrict__ out) {
  __shared__ float qsh[HD];
  __shared__ float sred[4][4];
  const int t = threadIdx.x;
  const int w = t >> 6, lane = t & 63;
  const int bb = blockIdx.x & 3;
  const int q = (int)((blockIdx.x * 997u + 13u) & 2047u);
  const int dc = (int)((blockIdx.x * 37u + 5u) & 127u);

  const unsigned short* qr = &qb[((size_t)bb * TQ + q) * HD];
  if (t < HD) qsh[t] = bf2f(qr[t]);
  __syncthreads();

  float mx1 = -1e30f, mx2 = -1e30f;
  for (int it = 0; it < 8; ++it) {
    int key = t + 256 * it;
    const unsigned* kr = (const unsigned*)&kb[((size_t)bb * TK + key) * HD];
    float s1 = 0.f, s2 = 0.f;
#pragma unroll 8
    for (int du = 0; du < 32; ++du) {
      unsigned u1 = kr[du], u2 = kr[32 + du];
      s1 += qsh[2 * du] * bf2f((unsigned short)u1) +
            qsh[2 * du + 1] * bf2f((unsigned short)(u1 >> 16));
      s2 += qsh[64 + 2 * du] * bf2f((unsigned short)u2) +
            qsh[64 + 2 * du + 1] * bf2f((unsigned short)(u2 >> 16));
    }
    mx1 = fmaxf(mx1, s1); mx2 = fmaxf(mx2, s2);
  }
  for (int o = 1; o < 64; o <<= 1) {
    mx1 = fmaxf(mx1, __shfl_xor(mx1, o));
    mx2 = fmaxf(mx2, __shfl_xor(mx2, o));
  }
  if (lane == 0) { sred[0][w] = mx1; sred[1][w] = mx2; }
  __syncthreads();
  mx1 = fmaxf(fmaxf(sred[0][0], sred[0][1]), fmaxf(sred[0][2], sred[0][3]));
  mx2 = fmaxf(fmaxf(sred[1][0], sred[1][1]), fmaxf(sred[1][2], sred[1][3]));
  __syncthreads();

  float l1 = 0.f, l2 = 0.f, o1 = 0.f, o2 = 0.f;
  for (int it = 0; it < 8; ++it) {
    int key = t + 256 * it;
    const unsigned* kr = (const unsigned*)&kb[((size_t)bb * TK + key) * HD];
    float s1 = 0.f, s2 = 0.f;
#pragma unroll 8
    for (int du = 0; du < 32; ++du) {
      unsigned u1 = kr[du], u2 = kr[32 + du];
      s1 += qsh[2 * du] * bf2f((unsigned short)u1) +
            qsh[2 * du + 1] * bf2f((unsigned short)(u1 >> 16));
      s2 += qsh[64 + 2 * du] * bf2f((unsigned short)u2) +
            qsh[64 + 2 * du + 1] * bf2f((unsigned short)(u2 >> 16));
    }
    float p1 = __expf(s1 - mx1), p2 = __expf(s2 - mx2);
    float v = bf2f(vbT[(size_t)dc * MQ + bb * TK + key]);
    l1 += p1; l2 += p2; o1 += p1 * v; o2 += p2 * v;
  }
  for (int o = 1; o < 64; o <<= 1) {
    l1 += __shfl_xor(l1, o); l2 += __shfl_xor(l2, o);
    o1 += __shfl_xor(o1, o); o2 += __shfl_xor(o2, o);
  }
  if (lane == 0) { sred[0][w] = l1; sred[1][w] = l2; sred[2][w] = o1; sred[3][w] = o2; }
  __syncthreads();
  if (t == 0) {
    l1 = sred[0][0] + sred[0][1] + sred[0][2] + sred[0][3];
    l2 = sred[1][0] + sred[1][1] + sred[1][2] + sred[1][3];
    o1 = sred[2][0] + sred[2][1] + sred[2][2] + sred[2][3];
    o2 = sred[3][0] + sred[3][1] + sred[3][2] + sred[3][3];
    float res = o1 / l1 - lamp[0] * (o2 / l2);
    float got = out[((size_t)bb * TQ + q) * HD + dc];
    if (!(fabsf(res - got) <= 0.02f)) out[0] = 1.0e7f;
  }
}

extern "C" void kernel_launch(void* const* d_in, const int* in_sizes, int n_in,
                              void* d_out, int out_size, void* d_ws, size_t ws_size,
                              hipStream_t stream) {
  const float* x    = (const float*)d_in[0];
  const float* enc  = (const float*)d_in[1];
  const float* Wq   = (const float*)d_in[2];
  const float* bq   = (const float*)d_in[3];
  const float* Wk   = (const float*)d_in[4];
  const float* bk   = (const float*)d_in[5];
  const float* Wv   = (const float*)d_in[6];
  const float* bv   = (const float*)d_in[7];
  const float* lq1  = (const float*)d_in[8];
  const float* lk1  = (const float*)d_in[9];
  const float* lq2  = (const float*)d_in[10];
  const float* lk2  = (const float*)d_in[11];
  const float* lini = (const float*)d_in[12];
  float* out = (float*)d_out;

  float* lam = (float*)d_ws;
  unsigned short* qb  = (unsigned short*)((char*)d_ws + 256);
  unsigned short* kb  = qb + (size_t)MQ * HD;
  unsigned short* vbT = kb + (size_t)MQ * HD;   // [128][8192]
  unsigned short* WqT = vbT + (size_t)MQ * HD;  // [128][1024] each
  unsigned short* WkT = WqT + (size_t)EMB * HD;
  unsigned short* WvT = WkT + (size_t)EMB * HD;

  hipLaunchKernelGGL(lam_kernel, dim3(1), dim3(64), 0, stream,
                     lq1, lk1, lq2, lk2, lini, lam);
  hipLaunchKernelGGL(cvtWT_kernel, dim3(512, 3), dim3(256), 0, stream,
                     Wq, Wk, Wv, WqT, WkT, WvT);
  hipLaunchKernelGGL(gemm_proj_kernel, dim3(MQ / 64, 3), dim3(256), 0, stream,
                     x, enc, WqT, WkT, WvT, bq, bk, bv, qb, kb, vbT);
  hipLaunchKernelGGL(attn_kernel, dim3(TQ / 64, 4), dim3(256), 0, stream,
                     qb, kb, vbT, lam, out);
  hipLaunchKernelGGL(attn_check_kernel, dim3(128), dim3(256), 0, stream,
                     qb, kb, vbT, lam, out);
}

// Round 8
// 299.789 us; speedup vs baseline: 5.5428x; 1.0184x over previous
//
#include <hip/hip_runtime.h>
#include <hip/hip_bf16.h>

// Problem: B=4, Tq=Tk=2048, E=1024, D=128, d=64. All inputs fp32, output fp32.
// Round 8: attention occupancy fix. Round-7 attn: 128 blocks on 256 CUs,
// 3 barriers/tile, Occupancy 5.7%, MfmaUtil 4.5% -> latency-bound.
// New attn: block = 16 q-rows, grid (TQ/16, B) = 512 blocks; 4 waves split
// the keys (512 each), barrier-free K-loop (K/V frags straight from global,
// L2-hot; P via per-wave LDS), flash-decoding LDS combine at the end.
//   gemm_proj/cvtWT/lam/tripwire unchanged (verified round 7).

#define TQ 2048
#define TK 2048
#define EMB 1024
#define HD 128
#define MQ 8192  // B*Tq rows

typedef __attribute__((ext_vector_type(8))) short short8;   // 8 bf16 = 4 VGPR
typedef __attribute__((ext_vector_type(4))) float floatx4;  // MFMA acc

__device__ __forceinline__ unsigned short f2bf(float f) {  // RNE fp32->bf16
  union { float f; unsigned u; } v; v.f = f;
  unsigned r = v.u + 0x7fffu + ((v.u >> 16) & 1u);
  return (unsigned short)(r >> 16);
}
__device__ __forceinline__ float bf2f(unsigned short s) {
  union { unsigned u; float f; } v; v.u = ((unsigned)s) << 16;
  return v.f;
}

// ---------------------------------------------------------------- lambda ----
__global__ void lam_kernel(const float* __restrict__ lq1, const float* __restrict__ lk1,
                           const float* __restrict__ lq2, const float* __restrict__ lk2,
                           const float* __restrict__ linit, float* __restrict__ lam_out) {
  int j = threadIdx.x;  // 64 threads
  float s1 = lq1[j] * lk1[j] + lq1[j + 64] * lk1[j + 64];
  float s2 = lq2[j] * lk2[j] + lq2[j + 64] * lk2[j + 64];
  for (int off = 1; off < 64; off <<= 1) {
    s1 += __shfl_xor(s1, off);
    s2 += __shfl_xor(s2, off);
  }
  if (j == 0) lam_out[0] = __expf(s1) - __expf(s2) + linit[0];
}

// -------------------------------------------------- weight convert+transpose
__global__ __launch_bounds__(256) void cvtWT_kernel(
    const float* __restrict__ Wq, const float* __restrict__ Wk,
    const float* __restrict__ Wv, unsigned short* __restrict__ WqT,
    unsigned short* __restrict__ WkT, unsigned short* __restrict__ WvT) {
  const int g = blockIdx.y;
  const float* W = (g == 0) ? Wq : (g == 1) ? Wk : Wv;
  unsigned short* WT = (g == 0) ? WqT : (g == 1) ? WkT : WvT;
  int idx = blockIdx.x * 256 + threadIdx.x;  // [0, 131072)
  int n = idx >> 10, k = idx & 1023;
  WT[idx] = f2bf(W[(size_t)k * HD + n]);
}

// -------------------------------------------------------- MFMA projections ----
__global__ __launch_bounds__(256) void gemm_proj_kernel(
    const float* __restrict__ x, const float* __restrict__ enc,
    const unsigned short* __restrict__ WqT, const unsigned short* __restrict__ WkT,
    const unsigned short* __restrict__ WvT,
    const float* __restrict__ bq, const float* __restrict__ bk,
    const float* __restrict__ bv,
    unsigned short* __restrict__ qb, unsigned short* __restrict__ kb,
    unsigned short* __restrict__ vbT) {
  __shared__ __align__(16) float Alsf[64][68];           // 17.4 KB (+4 pad)
  __shared__ __align__(16) unsigned short Bls[128][72];  // 18.4 KB (+8 pad)
  const int t = threadIdx.x;
  const int w = t >> 6, lane = t & 63;
  const int lo = lane & 15, quad = lane >> 4, q8 = quad * 8;
  const int g = blockIdx.y;
  const size_t m0 = (size_t)blockIdx.x * 64;
  const float* A = (g == 0) ? x : enc;
  const unsigned short* BT = (g == 0) ? WqT : (g == 1) ? WkT : WvT;
  const float* bias = (g == 0) ? bq : (g == 1) ? bk : bv;

  floatx4 acc[8];
  const floatx4 zz = {0.f, 0.f, 0.f, 0.f};
#pragma unroll
  for (int i = 0; i < 8; ++i) acc[i] = zz;

  for (int kt = 0; kt < EMB; kt += 64) {
#pragma unroll
    for (int i = 0; i < 4; ++i) {
      int idx = t + 256 * i;
      int row = idx >> 4, c4 = (idx & 15) * 4;
      *(float4*)&Alsf[row][c4] = *(const float4*)&A[(m0 + row) * EMB + kt + c4];
      int n = idx >> 3, c8 = (idx & 7) * 8;
      *(int4*)&Bls[n][c8] = *(const int4*)&BT[(size_t)n * EMB + kt + c8];
    }
    __syncthreads();

#pragma unroll
    for (int ks = 0; ks < 2; ++ks) {
      float4 fa = *(const float4*)&Alsf[16 * w + lo][ks * 32 + q8];
      float4 fb = *(const float4*)&Alsf[16 * w + lo][ks * 32 + q8 + 4];
      short8 af;
      af[0] = (short)f2bf(fa.x); af[1] = (short)f2bf(fa.y);
      af[2] = (short)f2bf(fa.z); af[3] = (short)f2bf(fa.w);
      af[4] = (short)f2bf(fb.x); af[5] = (short)f2bf(fb.y);
      af[6] = (short)f2bf(fb.z); af[7] = (short)f2bf(fb.w);
#pragma unroll
      for (int nt = 0; nt < 8; ++nt) {
        short8 bfr = *(const short8*)&Bls[nt * 16 + lo][ks * 32 + q8];
        acc[nt] = __builtin_amdgcn_mfma_f32_16x16x32_bf16(af, bfr, acc[nt], 0, 0, 0);
      }
    }
    __syncthreads();
  }

  const int mrow = 16 * w + quad * 4;
  if (g < 2) {
    unsigned short* Y = (g == 0) ? qb : kb;
    const float sc = (g == 0) ? 0.125f : 1.0f;
#pragma unroll
    for (int nt = 0; nt < 8; ++nt) {
      float bn = bias[nt * 16 + lo];
#pragma unroll
      for (int r = 0; r < 4; ++r)
        Y[(m0 + mrow + r) * HD + nt * 16 + lo] = f2bf((acc[nt][r] + bn) * sc);
    }
  } else {
#pragma unroll
    for (int nt = 0; nt < 8; ++nt) {
      float bn = bias[nt * 16 + lo];
      unsigned long long pk = 0;
#pragma unroll
      for (int r = 0; r < 4; ++r)
        pk |= (unsigned long long)f2bf(acc[nt][r] + bn) << (16 * r);
      *(unsigned long long*)&vbT[(size_t)(nt * 16 + lo) * MQ + m0 + mrow] = pk;
    }
  }
}

// ------------------------------------------------------------- attention ----
// grid (TQ/16, B) = 512 blocks, 256 threads (4 waves). Block owns 16 q-rows;
// wave w owns keys [512w, 512w+512). Barrier-free K-loop: K/V B-frags loaded
// directly from global (L2-hot, full 64B segments), P via per-wave LDS.
// End: flash-decoding combine of the 4 waves' (m,l,O) via LDS (5 barriers).
// MFMA 16x16x32 bf16 layouts (m89/m91/m120 verified):
//   A-frag: A[m=lane&15][k=quad*8+j]; B-frag: B[k=quad*8+j][n=lane&15]
//   C/D   : D[row=quad*4+r][col=lane&15]
__global__ __launch_bounds__(256) void attn_kernel(
    const unsigned short* __restrict__ qb, const unsigned short* __restrict__ kb,
    const unsigned short* __restrict__ vbT, const float* __restrict__ lam_ptr,
    float* __restrict__ out) {
  __shared__ __align__(16) unsigned char smem[33792];  // union: P | obuf
  __shared__ float mlbuf[4][16][4];                    // per-wave m1,l1,m2,l2
  __shared__ float rowstats[16][4];                    // M1,L1,M2,L2
  unsigned short (*Pls)[2][16][72] = (unsigned short (*)[2][16][72])smem;  // 18.4 KB
  float (*obuf)[16][132] = (float (*)[16][132])smem;                       // 33.8 KB

  const int t = threadIdx.x;
  const int w = t >> 6;
  const int lane = t & 63;
  const int lo = lane & 15;
  const int quad = lane >> 4;
  const int q8 = quad * 8;
  const int b = blockIdx.y;
  const int q0 = blockIdx.x * 16;
  const float lam = lam_ptr[0];
  const size_t kbase = (size_t)b * TK;

  // Q A-frags (qb pre-scaled by 0.125): rows q0..q0+15 shared by all waves
  const size_t qrow = (size_t)b * TQ + q0 + lo;
  short8 qf[2][2];
#pragma unroll
  for (int half = 0; half < 2; ++half)
#pragma unroll
    for (int ks = 0; ks < 2; ++ks)
      qf[half][ks] = *(const short8*)&qb[qrow * HD + half * 64 + ks * 32 + q8];

  floatx4 o1[8], o2[8];
  const floatx4 zz = {0.f, 0.f, 0.f, 0.f};
#pragma unroll
  for (int i = 0; i < 8; ++i) { o1[i] = zz; o2[i] = zz; }
  float m1[4], l1[4], m2[4], l2[4];
#pragma unroll
  for (int r = 0; r < 4; ++r) { m1[r] = m2[r] = -1e30f; l1[r] = l2[r] = 0.f; }

  const int kt0 = w * 512;
  for (int kt = kt0; kt < kt0 + 512; kt += 64) {
    // ---- QK^T from global K ----
    floatx4 s1[4], s2[4];
#pragma unroll
    for (int i = 0; i < 4; ++i) { s1[i] = zz; s2[i] = zz; }
#pragma unroll
    for (int ks = 0; ks < 2; ++ks)
#pragma unroll
      for (int nt = 0; nt < 4; ++nt) {
        const unsigned short* kp = &kb[(kbase + kt + nt * 16 + lo) * HD + ks * 32 + q8];
        short8 kf1 = *(const short8*)kp;
        short8 kf2 = *(const short8*)(kp + 64);
        s1[nt] = __builtin_amdgcn_mfma_f32_16x16x32_bf16(qf[0][ks], kf1, s1[nt], 0, 0, 0);
        s2[nt] = __builtin_amdgcn_mfma_f32_16x16x32_bf16(qf[1][ks], kf2, s2[nt], 0, 0, 0);
      }

    // ---- dual online softmax (rows quad*4+r, cols across lo) ----
#pragma unroll
    for (int r = 0; r < 4; ++r) {
      float a = fmaxf(fmaxf(s1[0][r], s1[1][r]), fmaxf(s1[2][r], s1[3][r]));
      float c2 = fmaxf(fmaxf(s2[0][r], s2[1][r]), fmaxf(s2[2][r], s2[3][r]));
#pragma unroll
      for (int o = 1; o < 16; o <<= 1) {
        a = fmaxf(a, __shfl_xor(a, o));
        c2 = fmaxf(c2, __shfl_xor(c2, o));
      }
      float mn1 = fmaxf(m1[r], a), mn2 = fmaxf(m2[r], c2);
      float al1 = __expf(m1[r] - mn1), al2 = __expf(m2[r] - mn2);
      m1[r] = mn1; m2[r] = mn2;
      float ls1 = 0.f, ls2 = 0.f;
#pragma unroll
      for (int nt = 0; nt < 4; ++nt) {
        float p1 = __expf(s1[nt][r] - mn1);
        float p2 = __expf(s2[nt][r] - mn2);
        ls1 += p1; ls2 += p2;
        Pls[w][0][quad * 4 + r][nt * 16 + lo] = f2bf(p1);
        Pls[w][1][quad * 4 + r][nt * 16 + lo] = f2bf(p2);
      }
#pragma unroll
      for (int o = 1; o < 16; o <<= 1) {
        ls1 += __shfl_xor(ls1, o);
        ls2 += __shfl_xor(ls2, o);
      }
      l1[r] = l1[r] * al1 + ls1;
      l2[r] = l2[r] * al2 + ls2;
#pragma unroll
      for (int nt = 0; nt < 8; ++nt) { o1[nt][r] *= al1; o2[nt][r] *= al2; }
    }

    // ---- PV from global V^T (per-wave P; same-wave LDS ordering, no barrier)
#pragma unroll
    for (int ks = 0; ks < 2; ++ks) {
      short8 p1 = *(const short8*)&Pls[w][0][lo][ks * 32 + q8];
      short8 p2 = *(const short8*)&Pls[w][1][lo][ks * 32 + q8];
#pragma unroll
      for (int nt = 0; nt < 8; ++nt) {
        short8 vf = *(const short8*)&vbT[(size_t)(nt * 16 + lo) * MQ + kbase + kt + ks * 32 + q8];
        o1[nt] = __builtin_amdgcn_mfma_f32_16x16x32_bf16(p1, vf, o1[nt], 0, 0, 0);
        o2[nt] = __builtin_amdgcn_mfma_f32_16x16x32_bf16(p2, vf, o2[nt], 0, 0, 0);
      }
    }
  }

  // ---- combine 4 waves' partials (flash-decoding merge) ----
  if (lo == 0) {
#pragma unroll
    for (int r = 0; r < 4; ++r) {
      mlbuf[w][quad * 4 + r][0] = m1[r];
      mlbuf[w][quad * 4 + r][1] = l1[r];
      mlbuf[w][quad * 4 + r][2] = m2[r];
      mlbuf[w][quad * 4 + r][3] = l2[r];
    }
  }
  __syncthreads();  // A: ml visible, all P reads done
  if (t < 16) {
    float M1 = -1e30f, M2 = -1e30f;
#pragma unroll
    for (int u = 0; u < 4; ++u) {
      M1 = fmaxf(M1, mlbuf[u][t][0]);
      M2 = fmaxf(M2, mlbuf[u][t][2]);
    }
    float L1 = 0.f, L2 = 0.f;
#pragma unroll
    for (int u = 0; u < 4; ++u) {
      L1 += mlbuf[u][t][1] * __expf(mlbuf[u][t][0] - M1);
      L2 += mlbuf[u][t][3] * __expf(mlbuf[u][t][2] - M2);
    }
    rowstats[t][0] = M1; rowstats[t][1] = L1;
    rowstats[t][2] = M2; rowstats[t][3] = L2;
  }
  __syncthreads();  // B

  // pass 1: softmax-1 partials
#pragma unroll
  for (int r = 0; r < 4; ++r) {
    int row = quad * 4 + r;
    float sc = __expf(m1[r] - rowstats[row][0]);
#pragma unroll
    for (int nt = 0; nt < 8; ++nt) obuf[w][row][nt * 16 + lo] = o1[nt][r] * sc;
  }
  __syncthreads();  // C
  float sum1[8];
#pragma unroll
  for (int i = 0; i < 8; ++i) {
    int e = t + 256 * i;
    int row = e >> 7, col = e & 127;
    sum1[i] = (obuf[0][row][col] + obuf[1][row][col] +
               obuf[2][row][col] + obuf[3][row][col]) / rowstats[row][1];
  }
  __syncthreads();  // D

  // pass 2: softmax-2 partials
#pragma unroll
  for (int r = 0; r < 4; ++r) {
    int row = quad * 4 + r;
    float sc = __expf(m2[r] - rowstats[row][2]);
#pragma unroll
    for (int nt = 0; nt < 8; ++nt) obuf[w][row][nt * 16 + lo] = o2[nt][r] * sc;
  }
  __syncthreads();  // E
#pragma unroll
  for (int i = 0; i < 8; ++i) {
    int e = t + 256 * i;
    int row = e >> 7, col = e & 127;
    float sum2 = (obuf[0][row][col] + obuf[1][row][col] +
                  obuf[2][row][col] + obuf[3][row][col]) / rowstats[row][3];
    out[((size_t)b * TQ + q0 + row) * HD + col] = sum1[i] - lam * sum2;
  }
}

// --------------------------------------------------------------- tripwire ----
__global__ __launch_bounds__(256) void attn_check_kernel(
    const unsigned short* __restrict__ qb, const unsigned short* __restrict__ kb,
    const unsigned short* __restrict__ vbT, const float* __restrict__ lamp,
    float* __restrict__ out) {
  __shared__ float qsh[HD];
  __shared__ float sred[4][4];
  const int t = threadIdx.x;
  const int w = t >> 6, lane = t & 63;
  const int bb = blockIdx.x & 3;
  const int q = (int)((blockIdx.x * 997u + 13u) & 2047u);
  const int dc = (int)((blockIdx.x * 37u + 5u) & 127u);

  const unsigned short* qr = &qb[((size_t)bb * TQ + q) * HD];
  if (t < HD) qsh[t] = bf2f(qr[t]);
  __syncthreads();

  float mx1 = -1e30f, mx2 = -1e30f;
  for (int it = 0; it < 8; ++it) {
    int key = t + 256 * it;
    const unsigned* kr = (const unsigned*)&kb[((size_t)bb * TK + key) * HD];
    float s1 = 0.f, s2 = 0.f;
#pragma unroll 8
    for (int du = 0; du < 32; ++du) {
      unsigned u1 = kr[du], u2 = kr[32 + du];
      s1 += qsh[2 * du] * bf2f((unsigned short)u1) +
            qsh[2 * du + 1] * bf2f((unsigned short)(u1 >> 16));
      s2 += qsh[64 + 2 * du] * bf2f((unsigned short)u2) +
            qsh[64 + 2 * du + 1] * bf2f((unsigned short)(u2 >> 16));
    }
    mx1 = fmaxf(mx1, s1); mx2 = fmaxf(mx2, s2);
  }
  for (int o = 1; o < 64; o <<= 1) {
    mx1 = fmaxf(mx1, __shfl_xor(mx1, o));
    mx2 = fmaxf(mx2, __shfl_xor(mx2, o));
  }
  if (lane == 0) { sred[0][w] = mx1; sred[1][w] = mx2; }
  __syncthreads();
  mx1 = fmaxf(fmaxf(sred[0][0], sred[0][1]), fmaxf(sred[0][2], sred[0][3]));
  mx2 = fmaxf(fmaxf(sred[1][0], sred[1][1]), fmaxf(sred[1][2], sred[1][3]));
  __syncthreads();

  float l1 = 0.f, l2 = 0.f, o1 = 0.f, o2 = 0.f;
  for (int it = 0; it < 8; ++it) {
    int key = t + 256 * it;
    const unsigned* kr = (const unsigned*)&kb[((size_t)bb * TK + key) * HD];
    float s1 = 0.f, s2 = 0.f;
#pragma unroll 8
    for (int du = 0; du < 32; ++du) {
      unsigned u1 = kr[du], u2 = kr[32 + du];
      s1 += qsh[2 * du] * bf2f((unsigned short)u1) +
            qsh[2 * du + 1] * bf2f((unsigned short)(u1 >> 16));
      s2 += qsh[64 + 2 * du] * bf2f((unsigned short)u2) +
            qsh[64 + 2 * du + 1] * bf2f((unsigned short)(u2 >> 16));
    }
    float p1 = __expf(s1 - mx1), p2 = __expf(s2 - mx2);
    float v = bf2f(vbT[(size_t)dc * MQ + bb * TK + key]);
    l1 += p1; l2 += p2; o1 += p1 * v; o2 += p2 * v;
  }
  for (int o = 1; o < 64; o <<= 1) {
    l1 += __shfl_xor(l1, o); l2 += __shfl_xor(l2, o);
    o1 += __shfl_xor(o1, o); o2 += __shfl_xor(o2, o);
  }
  if (lane == 0) { sred[0][w] = l1; sred[1][w] = l2; sred[2][w] = o1; sred[3][w] = o2; }
  __syncthreads();
  if (t == 0) {
    l1 = sred[0][0] + sred[0][1] + sred[0][2] + sred[0][3];
    l2 = sred[1][0] + sred[1][1] + sred[1][2] + sred[1][3];
    o1 = sred[2][0] + sred[2][1] + sred[2][2] + sred[2][3];
    o2 = sred[3][0] + sred[3][1] + sred[3][2] + sred[3][3];
    float res = o1 / l1 - lamp[0] * (o2 / l2);
    float got = out[((size_t)bb * TQ + q) * HD + dc];
    if (!(fabsf(res - got) <= 0.02f)) out[0] = 1.0e7f;
  }
}

extern "C" void kernel_launch(void* const* d_in, const int* in_sizes, int n_in,
                              void* d_out, int out_size, void* d_ws, size_t ws_size,
                              hipStream_t stream) {
  const float* x    = (const float*)d_in[0];
  const float* enc  = (const float*)d_in[1];
  const float* Wq   = (const float*)d_in[2];
  const float* bq   = (const float*)d_in[3];
  const float* Wk   = (const float*)d_in[4];
  const float* bk   = (const float*)d_in[5];
  const float* Wv   = (const float*)d_in[6];
  const float* bv   = (const float*)d_in[7];
  const float* lq1  = (const float*)d_in[8];
  const float* lk1  = (const float*)d_in[9];
  const float* lq2  = (const float*)d_in[10];
  const float* lk2  = (const float*)d_in[11];
  const float* lini = (const float*)d_in[12];
  float* out = (float*)d_out;

  float* lam = (float*)d_ws;
  unsigned short* qb  = (unsigned short*)((char*)d_ws + 256);
  unsigned short* kb  = qb + (size_t)MQ * HD;
  unsigned short* vbT = kb + (size_t)MQ * HD;   // [128][8192]
  unsigned short* WqT = vbT + (size_t)MQ * HD;  // [128][1024] each
  unsigned short* WkT = WqT + (size_t)EMB * HD;
  unsigned short* WvT = WkT + (size_t)EMB * HD;

  hipLaunchKernelGGL(lam_kernel, dim3(1), dim3(64), 0, stream,
                     lq1, lk1, lq2, lk2, lini, lam);
  hipLaunchKernelGGL(cvtWT_kernel, dim3(512, 3), dim3(256), 0, stream,
                     Wq, Wk, Wv, WqT, WkT, WvT);
  hipLaunchKernelGGL(gemm_proj_kernel, dim3(MQ / 64, 3), dim3(256), 0, stream,
                     x, enc, WqT, WkT, WvT, bq, bk, bv, qb, kb, vbT);
  hipLaunchKernelGGL(attn_kernel, dim3(TQ / 16, 4), dim3(256), 0, stream,
                     qb, kb, vbT, lam, out);
  hipLaunchKernelGGL(attn_check_kernel, dim3(128), dim3(256), 0, stream,
                     qb, kb, vbT, lam, out);
}

// Round 9
// 246.422 us; speedup vs baseline: 6.7432x; 1.2166x over previous
//
#include <hip/hip_runtime.h>
#include <hip/hip_bf16.h>

// Problem: B=4, Tq=Tk=2048, E=1024, D=128, d=64. All inputs fp32, output fp32.
// Round 9: flash-decoding attention. r7/r8 both stalled ~15k cyc per 64-key
// tile on global-load->MFMA round trips (MfmaUtil 4.6%). New attn: 64 q-rows
// per block, keys split across blocks (KS chosen from ws_size: 4/2/1), K/V
// cooperatively staged in LDS (bulk dwordx4 -> pipelined), 2 barriers/tile,
// P per-wave (no mid barrier, proven r8). Partials (m,l fp32 + O bf16) to ws;
// attn_combine_kernel merges. gemm_proj/cvtWT/lam/tripwire unchanged.

#define TQ 2048
#define TK 2048
#define EMB 1024
#define HD 128
#define MQ 8192  // B*Tq rows

typedef __attribute__((ext_vector_type(8))) short short8;   // 8 bf16 = 4 VGPR
typedef __attribute__((ext_vector_type(4))) float floatx4;  // MFMA acc

__device__ __forceinline__ unsigned short f2bf(float f) {  // RNE fp32->bf16
  union { float f; unsigned u; } v; v.f = f;
  unsigned r = v.u + 0x7fffu + ((v.u >> 16) & 1u);
  return (unsigned short)(r >> 16);
}
__device__ __forceinline__ float bf2f(unsigned short s) {
  union { unsigned u; float f; } v; v.u = ((unsigned)s) << 16;
  return v.f;
}

// ---------------------------------------------------------------- lambda ----
__global__ void lam_kernel(const float* __restrict__ lq1, const float* __restrict__ lk1,
                           const float* __restrict__ lq2, const float* __restrict__ lk2,
                           const float* __restrict__ linit, float* __restrict__ lam_out) {
  int j = threadIdx.x;  // 64 threads
  float s1 = lq1[j] * lk1[j] + lq1[j + 64] * lk1[j + 64];
  float s2 = lq2[j] * lk2[j] + lq2[j + 64] * lk2[j + 64];
  for (int off = 1; off < 64; off <<= 1) {
    s1 += __shfl_xor(s1, off);
    s2 += __shfl_xor(s2, off);
  }
  if (j == 0) lam_out[0] = __expf(s1) - __expf(s2) + linit[0];
}

// -------------------------------------------------- weight convert+transpose
__global__ __launch_bounds__(256) void cvtWT_kernel(
    const float* __restrict__ Wq, const float* __restrict__ Wk,
    const float* __restrict__ Wv, unsigned short* __restrict__ WqT,
    unsigned short* __restrict__ WkT, unsigned short* __restrict__ WvT) {
  const int g = blockIdx.y;
  const float* W = (g == 0) ? Wq : (g == 1) ? Wk : Wv;
  unsigned short* WT = (g == 0) ? WqT : (g == 1) ? WkT : WvT;
  int idx = blockIdx.x * 256 + threadIdx.x;  // [0, 131072)
  int n = idx >> 10, k = idx & 1023;
  WT[idx] = f2bf(W[(size_t)k * HD + n]);
}

// -------------------------------------------------------- MFMA projections ----
__global__ __launch_bounds__(256) void gemm_proj_kernel(
    const float* __restrict__ x, const float* __restrict__ enc,
    const unsigned short* __restrict__ WqT, const unsigned short* __restrict__ WkT,
    const unsigned short* __restrict__ WvT,
    const float* __restrict__ bq, const float* __restrict__ bk,
    const float* __restrict__ bv,
    unsigned short* __restrict__ qb, unsigned short* __restrict__ kb,
    unsigned short* __restrict__ vbT) {
  __shared__ __align__(16) float Alsf[64][68];           // 17.4 KB (+4 pad)
  __shared__ __align__(16) unsigned short Bls[128][72];  // 18.4 KB (+8 pad)
  const int t = threadIdx.x;
  const int w = t >> 6, lane = t & 63;
  const int lo = lane & 15, quad = lane >> 4, q8 = quad * 8;
  const int g = blockIdx.y;
  const size_t m0 = (size_t)blockIdx.x * 64;
  const float* A = (g == 0) ? x : enc;
  const unsigned short* BT = (g == 0) ? WqT : (g == 1) ? WkT : WvT;
  const float* bias = (g == 0) ? bq : (g == 1) ? bk : bv;

  floatx4 acc[8];
  const floatx4 zz = {0.f, 0.f, 0.f, 0.f};
#pragma unroll
  for (int i = 0; i < 8; ++i) acc[i] = zz;

  for (int kt = 0; kt < EMB; kt += 64) {
#pragma unroll
    for (int i = 0; i < 4; ++i) {
      int idx = t + 256 * i;
      int row = idx >> 4, c4 = (idx & 15) * 4;
      *(float4*)&Alsf[row][c4] = *(const float4*)&A[(m0 + row) * EMB + kt + c4];
      int n = idx >> 3, c8 = (idx & 7) * 8;
      *(int4*)&Bls[n][c8] = *(const int4*)&BT[(size_t)n * EMB + kt + c8];
    }
    __syncthreads();

#pragma unroll
    for (int ks = 0; ks < 2; ++ks) {
      float4 fa = *(const float4*)&Alsf[16 * w + lo][ks * 32 + q8];
      float4 fb = *(const float4*)&Alsf[16 * w + lo][ks * 32 + q8 + 4];
      short8 af;
      af[0] = (short)f2bf(fa.x); af[1] = (short)f2bf(fa.y);
      af[2] = (short)f2bf(fa.z); af[3] = (short)f2bf(fa.w);
      af[4] = (short)f2bf(fb.x); af[5] = (short)f2bf(fb.y);
      af[6] = (short)f2bf(fb.z); af[7] = (short)f2bf(fb.w);
#pragma unroll
      for (int nt = 0; nt < 8; ++nt) {
        short8 bfr = *(const short8*)&Bls[nt * 16 + lo][ks * 32 + q8];
        acc[nt] = __builtin_amdgcn_mfma_f32_16x16x32_bf16(af, bfr, acc[nt], 0, 0, 0);
      }
    }
    __syncthreads();
  }

  const int mrow = 16 * w + quad * 4;
  if (g < 2) {
    unsigned short* Y = (g == 0) ? qb : kb;
    const float sc = (g == 0) ? 0.125f : 1.0f;
#pragma unroll
    for (int nt = 0; nt < 8; ++nt) {
      float bn = bias[nt * 16 + lo];
#pragma unroll
      for (int r = 0; r < 4; ++r)
        Y[(m0 + mrow + r) * HD + nt * 16 + lo] = f2bf((acc[nt][r] + bn) * sc);
    }
  } else {
#pragma unroll
    for (int nt = 0; nt < 8; ++nt) {
      float bn = bias[nt * 16 + lo];
      unsigned long long pk = 0;
#pragma unroll
      for (int r = 0; r < 4; ++r)
        pk |= (unsigned long long)f2bf(acc[nt][r] + bn) << (16 * r);
      *(unsigned long long*)&vbT[(size_t)(nt * 16 + lo) * MQ + m0 + mrow] = pk;
    }
  }
}

// ---------------------------------------------------- attention (key-split) ----
// grid (TQ/64, B, KS), 256 thr (4 waves x 16 q-rows). Block processes nkeys
// keys starting at blockIdx.z*nkeys, staged per 64-key tile in LDS (coop,
// 2 barriers/tile). P per-wave in LDS (no barrier). Emits per-split partials:
// pstats = (m1,l1,m2,l2) fp32; pO1/pO2 = un-normalized O, bf16.
__global__ __launch_bounds__(256) void attn_split_kernel(
    const unsigned short* __restrict__ qb, const unsigned short* __restrict__ kb,
    const unsigned short* __restrict__ vbT,
    unsigned short* __restrict__ pO1, unsigned short* __restrict__ pO2,
    float4* __restrict__ pstats, int nkeys) {
  __shared__ __align__(16) unsigned short Kls[64][136];      // 17.4 KB
  __shared__ __align__(16) unsigned short Vt[128][72];       // 18.4 KB
  __shared__ __align__(16) unsigned short Pls[4][2][16][72]; // 18.4 KB

  const int t = threadIdx.x;
  const int w = t >> 6;
  const int lane = t & 63;
  const int lo = lane & 15;
  const int quad = lane >> 4;
  const int q8 = quad * 8;
  const int b = blockIdx.y;
  const int q0 = blockIdx.x * 64;
  const int ksp = blockIdx.z;
  const int kt0 = ksp * nkeys;
  const size_t kbase = (size_t)b * TK;

  const size_t qrow = (size_t)b * TQ + q0 + w * 16 + lo;
  short8 qf[2][2];
#pragma unroll
  for (int half = 0; half < 2; ++half)
#pragma unroll
    for (int ks = 0; ks < 2; ++ks)
      qf[half][ks] = *(const short8*)&qb[qrow * HD + half * 64 + ks * 32 + q8];

  floatx4 o1[8], o2[8];
  const floatx4 zz = {0.f, 0.f, 0.f, 0.f};
#pragma unroll
  for (int i = 0; i < 8; ++i) { o1[i] = zz; o2[i] = zz; }
  float m1[4], l1[4], m2[4], l2[4];
#pragma unroll
  for (int r = 0; r < 4; ++r) { m1[r] = m2[r] = -1e30f; l1[r] = l2[r] = 0.f; }

  for (int kt = kt0; kt < kt0 + nkeys; kt += 64) {
    // ---- cooperative stage: K (row-major) + V^T ----
#pragma unroll
    for (int i = 0; i < 4; ++i) {
      int c = t + 256 * i;
      int key = c >> 4, f0 = (c & 15) * 8;
      *(int4*)&Kls[key][f0] =
          *(const int4*)&kb[(kbase + kt + key) * HD + f0];
      int f = c >> 3, k0 = (c & 7) * 8;
      *(int4*)&Vt[f][k0] =
          *(const int4*)&vbT[(size_t)f * MQ + kbase + kt + k0];
    }
    __syncthreads();

    // ---- QK^T ----
    floatx4 s1[4], s2[4];
#pragma unroll
    for (int i = 0; i < 4; ++i) { s1[i] = zz; s2[i] = zz; }
#pragma unroll
    for (int ks = 0; ks < 2; ++ks)
#pragma unroll
      for (int nt = 0; nt < 4; ++nt) {
        short8 kf1 = *(const short8*)&Kls[nt * 16 + lo][ks * 32 + q8];
        short8 kf2 = *(const short8*)&Kls[nt * 16 + lo][64 + ks * 32 + q8];
        s1[nt] = __builtin_amdgcn_mfma_f32_16x16x32_bf16(qf[0][ks], kf1, s1[nt], 0, 0, 0);
        s2[nt] = __builtin_amdgcn_mfma_f32_16x16x32_bf16(qf[1][ks], kf2, s2[nt], 0, 0, 0);
      }

    // ---- dual online softmax (P per-wave; no barrier needed) ----
#pragma unroll
    for (int r = 0; r < 4; ++r) {
      float a = fmaxf(fmaxf(s1[0][r], s1[1][r]), fmaxf(s1[2][r], s1[3][r]));
      float c2 = fmaxf(fmaxf(s2[0][r], s2[1][r]), fmaxf(s2[2][r], s2[3][r]));
#pragma unroll
      for (int o = 1; o < 16; o <<= 1) {
        a = fmaxf(a, __shfl_xor(a, o));
        c2 = fmaxf(c2, __shfl_xor(c2, o));
      }
      float mn1 = fmaxf(m1[r], a), mn2 = fmaxf(m2[r], c2);
      float al1 = __expf(m1[r] - mn1), al2 = __expf(m2[r] - mn2);
      m1[r] = mn1; m2[r] = mn2;
      float ls1 = 0.f, ls2 = 0.f;
#pragma unroll
      for (int nt = 0; nt < 4; ++nt) {
        float p1 = __expf(s1[nt][r] - mn1);
        float p2 = __expf(s2[nt][r] - mn2);
        ls1 += p1; ls2 += p2;
        Pls[w][0][quad * 4 + r][nt * 16 + lo] = f2bf(p1);
        Pls[w][1][quad * 4 + r][nt * 16 + lo] = f2bf(p2);
      }
#pragma unroll
      for (int o = 1; o < 16; o <<= 1) {
        ls1 += __shfl_xor(ls1, o);
        ls2 += __shfl_xor(ls2, o);
      }
      l1[r] = l1[r] * al1 + ls1;
      l2[r] = l2[r] * al2 + ls2;
#pragma unroll
      for (int nt = 0; nt < 8; ++nt) { o1[nt][r] *= al1; o2[nt][r] *= al2; }
    }

    // ---- PV ----
#pragma unroll
    for (int ks = 0; ks < 2; ++ks) {
      short8 p1 = *(const short8*)&Pls[w][0][lo][ks * 32 + q8];
      short8 p2 = *(const short8*)&Pls[w][1][lo][ks * 32 + q8];
#pragma unroll
      for (int nt = 0; nt < 8; ++nt) {
        short8 vf = *(const short8*)&Vt[nt * 16 + lo][ks * 32 + q8];
        o1[nt] = __builtin_amdgcn_mfma_f32_16x16x32_bf16(p1, vf, o1[nt], 0, 0, 0);
        o2[nt] = __builtin_amdgcn_mfma_f32_16x16x32_bf16(p2, vf, o2[nt], 0, 0, 0);
      }
    }
    __syncthreads();  // protect Kls/Vt before next staging
  }

  // ---- emit partials ----
#pragma unroll
  for (int r = 0; r < 4; ++r) {
    int rowb = q0 + w * 16 + quad * 4 + r;           // row within batch
    size_t idx = ((size_t)(ksp * 4 + b)) * TQ + rowb;
    if (lo == 0) pstats[idx] = make_float4(m1[r], l1[r], m2[r], l2[r]);
#pragma unroll
    for (int nt = 0; nt < 8; ++nt) {
      pO1[idx * HD + nt * 16 + lo] = f2bf(o1[nt][r]);
      pO2[idx * HD + nt * 16 + lo] = f2bf(o2[nt][r]);
    }
  }
}

// ---------------------------------------------------------------- combine ----
// grid (TQ/16, B), 256 thr. Thread: row = q0 + t>>4, dims [8*(t&15), +8).
__global__ __launch_bounds__(256) void attn_combine_kernel(
    const unsigned short* __restrict__ pO1, const unsigned short* __restrict__ pO2,
    const float4* __restrict__ pstats, const float* __restrict__ lam_ptr,
    float* __restrict__ out, int ksn) {
  const int t = threadIdx.x;
  const int b = blockIdx.y;
  const int row = blockIdx.x * 16 + (t >> 4);
  const int dg = t & 15;

  float m1s[4], l1s[4], m2s[4], l2s[4];
  float M1 = -1e30f, M2 = -1e30f;
  for (int s = 0; s < ksn; ++s) {
    float4 f4 = pstats[((size_t)(s * 4 + b)) * TQ + row];
    m1s[s] = f4.x; l1s[s] = f4.y; m2s[s] = f4.z; l2s[s] = f4.w;
    M1 = fmaxf(M1, f4.x); M2 = fmaxf(M2, f4.z);
  }
  float L1 = 0.f, L2 = 0.f, e1[4], e2[4];
  for (int s = 0; s < ksn; ++s) {
    e1[s] = __expf(m1s[s] - M1); e2[s] = __expf(m2s[s] - M2);
    L1 += l1s[s] * e1[s]; L2 += l2s[s] * e2[s];
  }
  float a1[8], a2[8];
#pragma unroll
  for (int j = 0; j < 8; ++j) { a1[j] = 0.f; a2[j] = 0.f; }
  for (int s = 0; s < ksn; ++s) {
    size_t base = (((size_t)(s * 4 + b)) * TQ + row) * HD + dg * 8;
    int4 r1 = *(const int4*)&pO1[base];
    int4 r2 = *(const int4*)&pO2[base];
    const unsigned short* u1 = (const unsigned short*)&r1;
    const unsigned short* u2 = (const unsigned short*)&r2;
#pragma unroll
    for (int j = 0; j < 8; ++j) {
      a1[j] += bf2f(u1[j]) * e1[s];
      a2[j] += bf2f(u2[j]) * e2[s];
    }
  }
  const float i1 = 1.f / L1;
  const float i2 = lam_ptr[0] / L2;
  float4* op = (float4*)&out[((size_t)b * TQ + row) * HD + dg * 8];
  op[0] = make_float4(a1[0] * i1 - a2[0] * i2, a1[1] * i1 - a2[1] * i2,
                      a1[2] * i1 - a2[2] * i2, a1[3] * i1 - a2[3] * i2);
  op[1] = make_float4(a1[4] * i1 - a2[4] * i2, a1[5] * i1 - a2[5] * i2,
                      a1[6] * i1 - a2[6] * i2, a1[7] * i1 - a2[7] * i2);
}

// --------------------------------------------------------------- tripwire ----
__global__ __launch_bounds__(256) void attn_check_kernel(
    const unsigned short* __restrict__ qb, const unsigned short* __restrict__ kb,
    const unsigned short* __restrict__ vbT, const float* __restrict__ lamp,
    float* __restrict__ out) {
  __shared__ float qsh[HD];
  __shared__ float sred[4][4];
  const int t = threadIdx.x;
  const int w = t >> 6, lane = t & 63;
  const int bb = blockIdx.x & 3;
  const int q = (int)((blockIdx.x * 997u + 13u) & 2047u);
  const int dc = (int)((blockIdx.x * 37u + 5u) & 127u);

  const unsigned short* qr = &qb[((size_t)bb * TQ + q) * HD];
  if (t < HD) qsh[t] = bf2f(qr[t]);
  __syncthreads();

  float mx1 = -1e30f, mx2 = -1e30f;
  for (int it = 0; it < 8; ++it) {
    int key = t + 256 * it;
    const unsigned* kr = (const unsigned*)&kb[((size_t)bb * TK + key) * HD];
    float s1 = 0.f, s2 = 0.f;
#pragma unroll 8
    for (int du = 0; du < 32; ++du) {
      unsigned u1 = kr[du], u2 = kr[32 + du];
      s1 += qsh[2 * du] * bf2f((unsigned short)u1) +
            qsh[2 * du + 1] * bf2f((unsigned short)(u1 >> 16));
      s2 += qsh[64 + 2 * du] * bf2f((unsigned short)u2) +
            qsh[64 + 2 * du + 1] * bf2f((unsigned short)(u2 >> 16));
    }
    mx1 = fmaxf(mx1, s1); mx2 = fmaxf(mx2, s2);
  }
  for (int o = 1; o < 64; o <<= 1) {
    mx1 = fmaxf(mx1, __shfl_xor(mx1, o));
    mx2 = fmaxf(mx2, __shfl_xor(mx2, o));
  }
  if (lane == 0) { sred[0][w] = mx1; sred[1][w] = mx2; }
  __syncthreads();
  mx1 = fmaxf(fmaxf(sred[0][0], sred[0][1]), fmaxf(sred[0][2], sred[0][3]));
  mx2 = fmaxf(fmaxf(sred[1][0], sred[1][1]), fmaxf(sred[1][2], sred[1][3]));
  __syncthreads();

  float l1 = 0.f, l2 = 0.f, o1 = 0.f, o2 = 0.f;
  for (int it = 0; it < 8; ++it) {
    int key = t + 256 * it;
    const unsigned* kr = (const unsigned*)&kb[((size_t)bb * TK + key) * HD];
    float s1 = 0.f, s2 = 0.f;
#pragma unroll 8
    for (int du = 0; du < 32; ++du) {
      unsigned u1 = kr[du], u2 = kr[32 + du];
      s1 += qsh[2 * du] * bf2f((unsigned short)u1) +
            qsh[2 * du + 1] * bf2f((unsigned short)(u1 >> 16));
      s2 += qsh[64 + 2 * du] * bf2f((unsigned short)u2) +
            qsh[64 + 2 * du + 1] * bf2f((unsigned short)(u2 >> 16));
    }
    float p1 = __expf(s1 - mx1), p2 = __expf(s2 - mx2);
    float v = bf2f(vbT[(size_t)dc * MQ + bb * TK + key]);
    l1 += p1; l2 += p2; o1 += p1 * v; o2 += p2 * v;
  }
  for (int o = 1; o < 64; o <<= 1) {
    l1 += __shfl_xor(l1, o); l2 += __shfl_xor(l2, o);
    o1 += __shfl_xor(o1, o); o2 += __shfl_xor(o2, o);
  }
  if (lane == 0) { sred[0][w] = l1; sred[1][w] = l2; sred[2][w] = o1; sred[3][w] = o2; }
  __syncthreads();
  if (t == 0) {
    l1 = sred[0][0] + sred[0][1] + sred[0][2] + sred[0][3];
    l2 = sred[1][0] + sred[1][1] + sred[1][2] + sred[1][3];
    o1 = sred[2][0] + sred[2][1] + sred[2][2] + sred[2][3];
    o2 = sred[3][0] + sred[3][1] + sred[3][2] + sred[3][3];
    float res = o1 / l1 - lamp[0] * (o2 / l2);
    float got = out[((size_t)bb * TQ + q) * HD + dc];
    if (!(fabsf(res - got) <= 0.02f)) out[0] = 1.0e7f;
  }
}

extern "C" void kernel_launch(void* const* d_in, const int* in_sizes, int n_in,
                              void* d_out, int out_size, void* d_ws, size_t ws_size,
                              hipStream_t stream) {
  const float* x    = (const float*)d_in[0];
  const float* enc  = (const float*)d_in[1];
  const float* Wq   = (const float*)d_in[2];
  const float* bq   = (const float*)d_in[3];
  const float* Wk   = (const float*)d_in[4];
  const float* bk   = (const float*)d_in[5];
  const float* Wv   = (const float*)d_in[6];
  const float* bv   = (const float*)d_in[7];
  const float* lq1  = (const float*)d_in[8];
  const float* lk1  = (const float*)d_in[9];
  const float* lq2  = (const float*)d_in[10];
  const float* lk2  = (const float*)d_in[11];
  const float* lini = (const float*)d_in[12];
  float* out = (float*)d_out;

  char* p = (char*)d_ws;
  float* lam = (float*)p;                       p += 256;
  unsigned short* qb  = (unsigned short*)p;     p += (size_t)MQ * HD * 2;
  unsigned short* kb  = (unsigned short*)p;     p += (size_t)MQ * HD * 2;
  unsigned short* vbT = (unsigned short*)p;     p += (size_t)MQ * HD * 2;  // [128][8192]
  unsigned short* WqT = (unsigned short*)p;     p += (size_t)EMB * HD * 2;
  unsigned short* WkT = (unsigned short*)p;     p += (size_t)EMB * HD * 2;
  unsigned short* WvT = (unsigned short*)p;     p += (size_t)EMB * HD * 2;
  const size_t base_need = (size_t)(p - (char*)d_ws);

  // per-split partials: stats 4*TQ*16 B + two bf16 O planes 4*TQ*HD*2 B each
  const size_t per_ks = (size_t)4 * TQ * 16 + 2ull * 4 * TQ * HD * 2;
  int KS = 4;
  while (KS > 1 && base_need + (size_t)KS * per_ks > ws_size) KS >>= 1;

  float4* pstats = (float4*)p;                  p += (size_t)KS * 4 * TQ * 16;
  unsigned short* pO1 = (unsigned short*)p;     p += (size_t)KS * 4 * TQ * HD * 2;
  unsigned short* pO2 = (unsigned short*)p;

  hipLaunchKernelGGL(lam_kernel, dim3(1), dim3(64), 0, stream,
                     lq1, lk1, lq2, lk2, lini, lam);
  hipLaunchKernelGGL(cvtWT_kernel, dim3(512, 3), dim3(256), 0, stream,
                     Wq, Wk, Wv, WqT, WkT, WvT);
  hipLaunchKernelGGL(gemm_proj_kernel, dim3(MQ / 64, 3), dim3(256), 0, stream,
                     x, enc, WqT, WkT, WvT, bq, bk, bv, qb, kb, vbT);
  hipLaunchKernelGGL(attn_split_kernel, dim3(TQ / 64, 4, KS), dim3(256), 0, stream,
                     qb, kb, vbT, pO1, pO2, pstats, TK / KS);
  hipLaunchKernelGGL(attn_combine_kernel, dim3(TQ / 16, 4), dim3(256), 0, stream,
                     pO1, pO2, pstats, lam, out, KS);
  hipLaunchKernelGGL(attn_check_kernel, dim3(128), dim3(256), 0, stream,
                     qb, kb, vbT, lam, out);
}

// Round 10
// 229.973 us; speedup vs baseline: 7.2256x; 1.0715x over previous
//
#include <hip/hip_runtime.h>
#include <hip/hip_bf16.h>

// Problem: B=4, Tq=Tk=2048, E=1024, D=128, d=64. All inputs fp32, output fp32.
// Round 10: gemm_proj occupancy fix. r9 gemm_proj: 384 blocks on 256 CUs
// (1.2/CU resident), 16 barrier-paced iters -> latency-exposed (MfmaUtil 3.5%,
// VALUBusy 5%, HBM 8%). Now 32-row M-tiles: grid (256,3)=768 blocks=3/CU,
// 12 waves/CU; wave = (wm row-half, wn col-half); LDS 27 KB. Same K-order ->
// bitwise-identical outputs. attn flash-decoding split (r9) unchanged.

#define TQ 2048
#define TK 2048
#define EMB 1024
#define HD 128
#define MQ 8192  // B*Tq rows

typedef __attribute__((ext_vector_type(8))) short short8;   // 8 bf16 = 4 VGPR
typedef __attribute__((ext_vector_type(4))) float floatx4;  // MFMA acc

__device__ __forceinline__ unsigned short f2bf(float f) {  // RNE fp32->bf16
  union { float f; unsigned u; } v; v.f = f;
  unsigned r = v.u + 0x7fffu + ((v.u >> 16) & 1u);
  return (unsigned short)(r >> 16);
}
__device__ __forceinline__ float bf2f(unsigned short s) {
  union { unsigned u; float f; } v; v.u = ((unsigned)s) << 16;
  return v.f;
}

// ---------------------------------------------------------------- lambda ----
__global__ void lam_kernel(const float* __restrict__ lq1, const float* __restrict__ lk1,
                           const float* __restrict__ lq2, const float* __restrict__ lk2,
                           const float* __restrict__ linit, float* __restrict__ lam_out) {
  int j = threadIdx.x;  // 64 threads
  float s1 = lq1[j] * lk1[j] + lq1[j + 64] * lk1[j + 64];
  float s2 = lq2[j] * lk2[j] + lq2[j + 64] * lk2[j + 64];
  for (int off = 1; off < 64; off <<= 1) {
    s1 += __shfl_xor(s1, off);
    s2 += __shfl_xor(s2, off);
  }
  if (j == 0) lam_out[0] = __expf(s1) - __expf(s2) + linit[0];
}

// -------------------------------------------------- weight convert+transpose
__global__ __launch_bounds__(256) void cvtWT_kernel(
    const float* __restrict__ Wq, const float* __restrict__ Wk,
    const float* __restrict__ Wv, unsigned short* __restrict__ WqT,
    unsigned short* __restrict__ WkT, unsigned short* __restrict__ WvT) {
  const int g = blockIdx.y;
  const float* W = (g == 0) ? Wq : (g == 1) ? Wk : Wv;
  unsigned short* WT = (g == 0) ? WqT : (g == 1) ? WkT : WvT;
  int idx = blockIdx.x * 256 + threadIdx.x;  // [0, 131072)
  int n = idx >> 10, k = idx & 1023;
  WT[idx] = f2bf(W[(size_t)k * HD + n]);
}

// -------------------------------------------------------- MFMA projections ----
// grid (MQ/32, 3), 256 thr (4 waves). wave w: wm=w&1 -> rows 16wm..+16,
// wn=w>>1 -> cols 64wn..+64. Per K-iter (BK=64): stage A fp32 32x64 (8KB) +
// B^T bf16 128x64 (16KB); 8 MFMA/wave. g=0: qb*(0.125); g=1: kb; g=2: vbT^T.
__global__ __launch_bounds__(256) void gemm_proj_kernel(
    const float* __restrict__ x, const float* __restrict__ enc,
    const unsigned short* __restrict__ WqT, const unsigned short* __restrict__ WkT,
    const unsigned short* __restrict__ WvT,
    const float* __restrict__ bq, const float* __restrict__ bk,
    const float* __restrict__ bv,
    unsigned short* __restrict__ qb, unsigned short* __restrict__ kb,
    unsigned short* __restrict__ vbT) {
  __shared__ __align__(16) float Alsf[32][68];           // 8.7 KB (+4 pad)
  __shared__ __align__(16) unsigned short Bls[128][72];  // 18.4 KB (+8 pad)
  const int t = threadIdx.x;
  const int w = t >> 6, lane = t & 63;
  const int lo = lane & 15, quad = lane >> 4, q8 = quad * 8;
  const int wm = w & 1, wn = w >> 1;
  const int g = blockIdx.y;
  const size_t m0 = (size_t)blockIdx.x * 32;
  const float* A = (g == 0) ? x : enc;
  const unsigned short* BT = (g == 0) ? WqT : (g == 1) ? WkT : WvT;
  const float* bias = (g == 0) ? bq : (g == 1) ? bk : bv;

  floatx4 acc[4];
  const floatx4 zz = {0.f, 0.f, 0.f, 0.f};
#pragma unroll
  for (int i = 0; i < 4; ++i) acc[i] = zz;

  for (int kt = 0; kt < EMB; kt += 64) {
    // stage A (fp32 32x64, 512 float4) + B^T (bf16 128x64, 1024 int4)
#pragma unroll
    for (int i = 0; i < 2; ++i) {
      int c = t + 256 * i;
      int row = c >> 4, c4 = (c & 15) * 4;
      *(float4*)&Alsf[row][c4] = *(const float4*)&A[(m0 + row) * EMB + kt + c4];
    }
#pragma unroll
    for (int i = 0; i < 4; ++i) {
      int c = t + 256 * i;
      int n = c >> 3, c8 = (c & 7) * 8;
      *(int4*)&Bls[n][c8] = *(const int4*)&BT[(size_t)n * EMB + kt + c8];
    }
    __syncthreads();

#pragma unroll
    for (int ks = 0; ks < 2; ++ks) {
      float4 fa = *(const float4*)&Alsf[16 * wm + lo][ks * 32 + q8];
      float4 fb = *(const float4*)&Alsf[16 * wm + lo][ks * 32 + q8 + 4];
      short8 af;
      af[0] = (short)f2bf(fa.x); af[1] = (short)f2bf(fa.y);
      af[2] = (short)f2bf(fa.z); af[3] = (short)f2bf(fa.w);
      af[4] = (short)f2bf(fb.x); af[5] = (short)f2bf(fb.y);
      af[6] = (short)f2bf(fb.z); af[7] = (short)f2bf(fb.w);
#pragma unroll
      for (int nt = 0; nt < 4; ++nt) {
        short8 bfr = *(const short8*)&Bls[wn * 64 + nt * 16 + lo][ks * 32 + q8];
        acc[nt] = __builtin_amdgcn_mfma_f32_16x16x32_bf16(af, bfr, acc[nt], 0, 0, 0);
      }
    }
    __syncthreads();
  }

  // epilogue: rows m0+16wm+quad*4+r, cols 64wn+nt*16+lo
  const int mrow = 16 * wm + quad * 4;
  if (g < 2) {
    unsigned short* Y = (g == 0) ? qb : kb;
    const float sc = (g == 0) ? 0.125f : 1.0f;
#pragma unroll
    for (int nt = 0; nt < 4; ++nt) {
      float bn = bias[wn * 64 + nt * 16 + lo];
#pragma unroll
      for (int r = 0; r < 4; ++r)
        Y[(m0 + mrow + r) * HD + wn * 64 + nt * 16 + lo] = f2bf((acc[nt][r] + bn) * sc);
    }
  } else {
#pragma unroll
    for (int nt = 0; nt < 4; ++nt) {
      float bn = bias[wn * 64 + nt * 16 + lo];
      unsigned long long pk = 0;
#pragma unroll
      for (int r = 0; r < 4; ++r)
        pk |= (unsigned long long)f2bf(acc[nt][r] + bn) << (16 * r);
      *(unsigned long long*)&vbT[(size_t)(wn * 64 + nt * 16 + lo) * MQ + m0 + mrow] = pk;
    }
  }
}

// ---------------------------------------------------- attention (key-split) ----
// Unchanged round-9 kernel (verified).
__global__ __launch_bounds__(256) void attn_split_kernel(
    const unsigned short* __restrict__ qb, const unsigned short* __restrict__ kb,
    const unsigned short* __restrict__ vbT,
    unsigned short* __restrict__ pO1, unsigned short* __restrict__ pO2,
    float4* __restrict__ pstats, int nkeys) {
  __shared__ __align__(16) unsigned short Kls[64][136];      // 17.4 KB
  __shared__ __align__(16) unsigned short Vt[128][72];       // 18.4 KB
  __shared__ __align__(16) unsigned short Pls[4][2][16][72]; // 18.4 KB

  const int t = threadIdx.x;
  const int w = t >> 6;
  const int lane = t & 63;
  const int lo = lane & 15;
  const int quad = lane >> 4;
  const int q8 = quad * 8;
  const int b = blockIdx.y;
  const int q0 = blockIdx.x * 64;
  const int ksp = blockIdx.z;
  const int kt0 = ksp * nkeys;
  const size_t kbase = (size_t)b * TK;

  const size_t qrow = (size_t)b * TQ + q0 + w * 16 + lo;
  short8 qf[2][2];
#pragma unroll
  for (int half = 0; half < 2; ++half)
#pragma unroll
    for (int ks = 0; ks < 2; ++ks)
      qf[half][ks] = *(const short8*)&qb[qrow * HD + half * 64 + ks * 32 + q8];

  floatx4 o1[8], o2[8];
  const floatx4 zz = {0.f, 0.f, 0.f, 0.f};
#pragma unroll
  for (int i = 0; i < 8; ++i) { o1[i] = zz; o2[i] = zz; }
  float m1[4], l1[4], m2[4], l2[4];
#pragma unroll
  for (int r = 0; r < 4; ++r) { m1[r] = m2[r] = -1e30f; l1[r] = l2[r] = 0.f; }

  for (int kt = kt0; kt < kt0 + nkeys; kt += 64) {
#pragma unroll
    for (int i = 0; i < 4; ++i) {
      int c = t + 256 * i;
      int key = c >> 4, f0 = (c & 15) * 8;
      *(int4*)&Kls[key][f0] =
          *(const int4*)&kb[(kbase + kt + key) * HD + f0];
      int f = c >> 3, k0 = (c & 7) * 8;
      *(int4*)&Vt[f][k0] =
          *(const int4*)&vbT[(size_t)f * MQ + kbase + kt + k0];
    }
    __syncthreads();

    floatx4 s1[4], s2[4];
#pragma unroll
    for (int i = 0; i < 4; ++i) { s1[i] = zz; s2[i] = zz; }
#pragma unroll
    for (int ks = 0; ks < 2; ++ks)
#pragma unroll
      for (int nt = 0; nt < 4; ++nt) {
        short8 kf1 = *(const short8*)&Kls[nt * 16 + lo][ks * 32 + q8];
        short8 kf2 = *(const short8*)&Kls[nt * 16 + lo][64 + ks * 32 + q8];
        s1[nt] = __builtin_amdgcn_mfma_f32_16x16x32_bf16(qf[0][ks], kf1, s1[nt], 0, 0, 0);
        s2[nt] = __builtin_amdgcn_mfma_f32_16x16x32_bf16(qf[1][ks], kf2, s2[nt], 0, 0, 0);
      }

#pragma unroll
    for (int r = 0; r < 4; ++r) {
      float a = fmaxf(fmaxf(s1[0][r], s1[1][r]), fmaxf(s1[2][r], s1[3][r]));
      float c2 = fmaxf(fmaxf(s2[0][r], s2[1][r]), fmaxf(s2[2][r], s2[3][r]));
#pragma unroll
      for (int o = 1; o < 16; o <<= 1) {
        a = fmaxf(a, __shfl_xor(a, o));
        c2 = fmaxf(c2, __shfl_xor(c2, o));
      }
      float mn1 = fmaxf(m1[r], a), mn2 = fmaxf(m2[r], c2);
      float al1 = __expf(m1[r] - mn1), al2 = __expf(m2[r] - mn2);
      m1[r] = mn1; m2[r] = mn2;
      float ls1 = 0.f, ls2 = 0.f;
#pragma unroll
      for (int nt = 0; nt < 4; ++nt) {
        float p1 = __expf(s1[nt][r] - mn1);
        float p2 = __expf(s2[nt][r] - mn2);
        ls1 += p1; ls2 += p2;
        Pls[w][0][quad * 4 + r][nt * 16 + lo] = f2bf(p1);
        Pls[w][1][quad * 4 + r][nt * 16 + lo] = f2bf(p2);
      }
#pragma unroll
      for (int o = 1; o < 16; o <<= 1) {
        ls1 += __shfl_xor(ls1, o);
        ls2 += __shfl_xor(ls2, o);
      }
      l1[r] = l1[r] * al1 + ls1;
      l2[r] = l2[r] * al2 + ls2;
#pragma unroll
      for (int nt = 0; nt < 8; ++nt) { o1[nt][r] *= al1; o2[nt][r] *= al2; }
    }

#pragma unroll
    for (int ks = 0; ks < 2; ++ks) {
      short8 p1 = *(const short8*)&Pls[w][0][lo][ks * 32 + q8];
      short8 p2 = *(const short8*)&Pls[w][1][lo][ks * 32 + q8];
#pragma unroll
      for (int nt = 0; nt < 8; ++nt) {
        short8 vf = *(const short8*)&Vt[nt * 16 + lo][ks * 32 + q8];
        o1[nt] = __builtin_amdgcn_mfma_f32_16x16x32_bf16(p1, vf, o1[nt], 0, 0, 0);
        o2[nt] = __builtin_amdgcn_mfma_f32_16x16x32_bf16(p2, vf, o2[nt], 0, 0, 0);
      }
    }
    __syncthreads();
  }

#pragma unroll
  for (int r = 0; r < 4; ++r) {
    int rowb = q0 + w * 16 + quad * 4 + r;
    size_t idx = ((size_t)(ksp * 4 + b)) * TQ + rowb;
    if (lo == 0) pstats[idx] = make_float4(m1[r], l1[r], m2[r], l2[r]);
#pragma unroll
    for (int nt = 0; nt < 8; ++nt) {
      pO1[idx * HD + nt * 16 + lo] = f2bf(o1[nt][r]);
      pO2[idx * HD + nt * 16 + lo] = f2bf(o2[nt][r]);
    }
  }
}

// ---------------------------------------------------------------- combine ----
__global__ __launch_bounds__(256) void attn_combine_kernel(
    const unsigned short* __restrict__ pO1, const unsigned short* __restrict__ pO2,
    const float4* __restrict__ pstats, const float* __restrict__ lam_ptr,
    float* __restrict__ out, int ksn) {
  const int t = threadIdx.x;
  const int b = blockIdx.y;
  const int row = blockIdx.x * 16 + (t >> 4);
  const int dg = t & 15;

  float m1s[4], l1s[4], m2s[4], l2s[4];
  float M1 = -1e30f, M2 = -1e30f;
  for (int s = 0; s < ksn; ++s) {
    float4 f4 = pstats[((size_t)(s * 4 + b)) * TQ + row];
    m1s[s] = f4.x; l1s[s] = f4.y; m2s[s] = f4.z; l2s[s] = f4.w;
    M1 = fmaxf(M1, f4.x); M2 = fmaxf(M2, f4.z);
  }
  float L1 = 0.f, L2 = 0.f, e1[4], e2[4];
  for (int s = 0; s < ksn; ++s) {
    e1[s] = __expf(m1s[s] - M1); e2[s] = __expf(m2s[s] - M2);
    L1 += l1s[s] * e1[s]; L2 += l2s[s] * e2[s];
  }
  float a1[8], a2[8];
#pragma unroll
  for (int j = 0; j < 8; ++j) { a1[j] = 0.f; a2[j] = 0.f; }
  for (int s = 0; s < ksn; ++s) {
    size_t base = (((size_t)(s * 4 + b)) * TQ + row) * HD + dg * 8;
    int4 r1 = *(const int4*)&pO1[base];
    int4 r2 = *(const int4*)&pO2[base];
    const unsigned short* u1 = (const unsigned short*)&r1;
    const unsigned short* u2 = (const unsigned short*)&r2;
#pragma unroll
    for (int j = 0; j < 8; ++j) {
      a1[j] += bf2f(u1[j]) * e1[s];
      a2[j] += bf2f(u2[j]) * e2[s];
    }
  }
  const float i1 = 1.f / L1;
  const float i2 = lam_ptr[0] / L2;
  float4* op = (float4*)&out[((size_t)b * TQ + row) * HD + dg * 8];
  op[0] = make_float4(a1[0] * i1 - a2[0] * i2, a1[1] * i1 - a2[1] * i2,
                      a1[2] * i1 - a2[2] * i2, a1[3] * i1 - a2[3] * i2);
  op[1] = make_float4(a1[4] * i1 - a2[4] * i2, a1[5] * i1 - a2[5] * i2,
                      a1[6] * i1 - a2[6] * i2, a1[7] * i1 - a2[7] * i2);
}

// --------------------------------------------------------------- tripwire ----
__global__ __launch_bounds__(256) void attn_check_kernel(
    const unsigned short* __restrict__ qb, const unsigned short* __restrict__ kb,
    const unsigned short* __restrict__ vbT, const float* __restrict__ lamp,
    float* __restrict__ out) {
  __shared__ float qsh[HD];
  __shared__ float sred[4][4];
  const int t = threadIdx.x;
  const int w = t >> 6, lane = t & 63;
  const int bb = blockIdx.x & 3;
  const int q = (int)((blockIdx.x * 997u + 13u) & 2047u);
  const int dc = (int)((blockIdx.x * 37u + 5u) & 127u);

  const unsigned short* qr = &qb[((size_t)bb * TQ + q) * HD];
  if (t < HD) qsh[t] = bf2f(qr[t]);
  __syncthreads();

  float mx1 = -1e30f, mx2 = -1e30f;
  for (int it = 0; it < 8; ++it) {
    int key = t + 256 * it;
    const unsigned* kr = (const unsigned*)&kb[((size_t)bb * TK + key) * HD];
    float s1 = 0.f, s2 = 0.f;
#pragma unroll 8
    for (int du = 0; du < 32; ++du) {
      unsigned u1 = kr[du], u2 = kr[32 + du];
      s1 += qsh[2 * du] * bf2f((unsigned short)u1) +
            qsh[2 * du + 1] * bf2f((unsigned short)(u1 >> 16));
      s2 += qsh[64 + 2 * du] * bf2f((unsigned short)u2) +
            qsh[64 + 2 * du + 1] * bf2f((unsigned short)(u2 >> 16));
    }
    mx1 = fmaxf(mx1, s1); mx2 = fmaxf(mx2, s2);
  }
  for (int o = 1; o < 64; o <<= 1) {
    mx1 = fmaxf(mx1, __shfl_xor(mx1, o));
    mx2 = fmaxf(mx2, __shfl_xor(mx2, o));
  }
  if (lane == 0) { sred[0][w] = mx1; sred[1][w] = mx2; }
  __syncthreads();
  mx1 = fmaxf(fmaxf(sred[0][0], sred[0][1]), fmaxf(sred[0][2], sred[0][3]));
  mx2 = fmaxf(fmaxf(sred[1][0], sred[1][1]), fmaxf(sred[1][2], sred[1][3]));
  __syncthreads();

  float l1 = 0.f, l2 = 0.f, o1 = 0.f, o2 = 0.f;
  for (int it = 0; it < 8; ++it) {
    int key = t + 256 * it;
    const unsigned* kr = (const unsigned*)&kb[((size_t)bb * TK + key) * HD];
    float s1 = 0.f, s2 = 0.f;
#pragma unroll 8
    for (int du = 0; du < 32; ++du) {
      unsigned u1 = kr[du], u2 = kr[32 + du];
      s1 += qsh[2 * du] * bf2f((unsigned short)u1) +
            qsh[2 * du + 1] * bf2f((unsigned short)(u1 >> 16));
      s2 += qsh[64 + 2 * du] * bf2f((unsigned short)u2) +
            qsh[64 + 2 * du + 1] * bf2f((unsigned short)(u2 >> 16));
    }
    float p1 = __expf(s1 - mx1), p2 = __expf(s2 - mx2);
    float v = bf2f(vbT[(size_t)dc * MQ + bb * TK + key]);
    l1 += p1; l2 += p2; o1 += p1 * v; o2 += p2 * v;
  }
  for (int o = 1; o < 64; o <<= 1) {
    l1 += __shfl_xor(l1, o); l2 += __shfl_xor(l2, o);
    o1 += __shfl_xor(o1, o); o2 += __shfl_xor(o2, o);
  }
  if (lane == 0) { sred[0][w] = l1; sred[1][w] = l2; sred[2][w] = o1; sred[3][w] = o2; }
  __syncthreads();
  if (t == 0) {
    l1 = sred[0][0] + sred[0][1] + sred[0][2] + sred[0][3];
    l2 = sred[1][0] + sred[1][1] + sred[1][2] + sred[1][3];
    o1 = sred[2][0] + sred[2][1] + sred[2][2] + sred[2][3];
    o2 = sred[3][0] + sred[3][1] + sred[3][2] + sred[3][3];
    float res = o1 / l1 - lamp[0] * (o2 / l2);
    float got = out[((size_t)bb * TQ + q) * HD + dc];
    if (!(fabsf(res - got) <= 0.02f)) out[0] = 1.0e7f;
  }
}

extern "C" void kernel_launch(void* const* d_in, const int* in_sizes, int n_in,
                              void* d_out, int out_size, void* d_ws, size_t ws_size,
                              hipStream_t stream) {
  const float* x    = (const float*)d_in[0];
  const float* enc  = (const float*)d_in[1];
  const float* Wq   = (const float*)d_in[2];
  const float* bq   = (const float*)d_in[3];
  const float* Wk   = (const float*)d_in[4];
  const float* bk   = (const float*)d_in[5];
  const float* Wv   = (const float*)d_in[6];
  const float* bv   = (const float*)d_in[7];
  const float* lq1  = (const float*)d_in[8];
  const float* lk1  = (const float*)d_in[9];
  const float* lq2  = (const float*)d_in[10];
  const float* lk2  = (const float*)d_in[11];
  const float* lini = (const float*)d_in[12];
  float* out = (float*)d_out;

  char* p = (char*)d_ws;
  float* lam = (float*)p;                       p += 256;
  unsigned short* qb  = (unsigned short*)p;     p += (size_t)MQ * HD * 2;
  unsigned short* kb  = (unsigned short*)p;     p += (size_t)MQ * HD * 2;
  unsigned short* vbT = (unsigned short*)p;     p += (size_t)MQ * HD * 2;  // [128][8192]
  unsigned short* WqT = (unsigned short*)p;     p += (size_t)EMB * HD * 2;
  unsigned short* WkT = (unsigned short*)p;     p += (size_t)EMB * HD * 2;
  unsigned short* WvT = (unsigned short*)p;     p += (size_t)EMB * HD * 2;
  const size_t base_need = (size_t)(p - (char*)d_ws);

  const size_t per_ks = (size_t)4 * TQ * 16 + 2ull * 4 * TQ * HD * 2;
  int KS = 4;
  while (KS > 1 && base_need + (size_t)KS * per_ks > ws_size) KS >>= 1;

  float4* pstats = (float4*)p;                  p += (size_t)KS * 4 * TQ * 16;
  unsigned short* pO1 = (unsigned short*)p;     p += (size_t)KS * 4 * TQ * HD * 2;
  unsigned short* pO2 = (unsigned short*)p;

  hipLaunchKernelGGL(lam_kernel, dim3(1), dim3(64), 0, stream,
                     lq1, lk1, lq2, lk2, lini, lam);
  hipLaunchKernelGGL(cvtWT_kernel, dim3(512, 3), dim3(256), 0, stream,
                     Wq, Wk, Wv, WqT, WkT, WvT);
  hipLaunchKernelGGL(gemm_proj_kernel, dim3(MQ / 32, 3), dim3(256), 0, stream,
                     x, enc, WqT, WkT, WvT, bq, bk, bv, qb, kb, vbT);
  hipLaunchKernelGGL(attn_split_kernel, dim3(TQ / 64, 4, KS), dim3(256), 0, stream,
                     qb, kb, vbT, pO1, pO2, pstats, TK / KS);
  hipLaunchKernelGGL(attn_combine_kernel, dim3(TQ / 16, 4), dim3(256), 0, stream,
                     pO1, pO2, pstats, lam, out, KS);
  hipLaunchKernelGGL(attn_check_kernel, dim3(128), dim3(256), 0, stream,
                     qb, kb, vbT, lam, out);
}